// Round 1
// baseline (10700.394 us; speedup 1.0000x reference)
//
#include <hip/hip_runtime.h>
#include <hip/hip_cooperative_groups.h>

namespace cg = cooperative_groups;

#define Bb 256
#define Tt 128
#define Dd 512
#define Uu 1024

// ---------------- Kernel 1: xi = x @ W_i + b -> written into d_out[b][t][u] ----------
// M = B*T = 32768, K = D = 512, N = U = 1024.  BM=BN=64, BK=16, 256 thr, 4x4/thread.
__global__ __launch_bounds__(256, 1) void xi_gemm_kernel(
    const float* __restrict__ x, const float* __restrict__ Wi,
    const float* __restrict__ bias, float* __restrict__ out)
{
    __shared__ __align__(16) float As[16][64];   // [k][m]
    __shared__ __align__(16) float Bs[16][64];   // [k][n]
    const int tid  = threadIdx.x;
    const int row0 = blockIdx.x * 64;
    const int col0 = blockIdx.y * 64;
    const int tr = tid >> 4;       // 0..15
    const int tc = tid & 15;       // 0..15
    // staging indices
    const int ra  = tid & 63;      // A row 0..63
    const int k4a = tid >> 6;      // A k-float4 0..3
    const int kb  = tid >> 4;      // B k row 0..15
    const int c4b = tid & 15;      // B col-float4 0..15

    float acc[4][4] = {};

    for (int k0 = 0; k0 < Dd; k0 += 16) {
        float4 av = *reinterpret_cast<const float4*>(&x[(size_t)(row0 + ra) * Dd + k0 + k4a * 4]);
        float4 bv = *reinterpret_cast<const float4*>(&Wi[(size_t)(k0 + kb) * Uu + col0 + c4b * 4]);
        __syncthreads();           // previous iter's LDS reads done
        As[k4a*4+0][ra] = av.x;
        As[k4a*4+1][ra] = av.y;
        As[k4a*4+2][ra] = av.z;
        As[k4a*4+3][ra] = av.w;
        *reinterpret_cast<float4*>(&Bs[kb][c4b*4]) = bv;
        __syncthreads();
        #pragma unroll
        for (int kk = 0; kk < 16; ++kk) {
            float4 a = *reinterpret_cast<const float4*>(&As[kk][tr*4]);
            float4 b = *reinterpret_cast<const float4*>(&Bs[kk][tc*4]);
            float aa[4] = {a.x, a.y, a.z, a.w};
            float bb[4] = {b.x, b.y, b.z, b.w};
            #pragma unroll
            for (int i = 0; i < 4; ++i)
                #pragma unroll
                for (int j = 0; j < 4; ++j)
                    acc[i][j] += aa[i] * bb[j];
        }
    }

    float4 bv = *reinterpret_cast<const float4*>(&bias[col0 + tc*4]);
    #pragma unroll
    for (int i = 0; i < 4; ++i) {
        float4 o;
        o.x = acc[i][0] + bv.x;  o.y = acc[i][1] + bv.y;
        o.z = acc[i][2] + bv.z;  o.w = acc[i][3] + bv.w;
        *reinterpret_cast<float4*>(&out[(size_t)(row0 + tr*4 + i) * Uu + col0 + tc*4]) = o;
    }
}

// ---------------- Kernel 2: cooperative scan over T ----------------
// Per step: C[256,1024] = H @ Wr  (diag of Wr corrected after the fact),
// iz = xi + C, out = clip(iz^2 - iz, -1, 1), stored into d_out[:,t,:].
// Grid: 256 wgs (8 Mtiles x 32 Ntiles of 32x32), 256 thr; the 4 waves split K
// (256 each) with wave-private LDS staging, then block reduce + pointwise.
__global__ __launch_bounds__(256, 1) void scan_kernel(
    const float* __restrict__ Wr, const float* __restrict__ h0,
    float* __restrict__ out)
{
    cg::grid_group grid = cg::this_grid();
    __shared__ __align__(16) float As[4][64][32];   // per-wave [k][m], reused as partial store
    __shared__ __align__(16) float Bs[4][64][32];   // per-wave [k][n]

    const int tid  = threadIdx.x;
    const int w    = tid >> 6;           // wave 0..3
    const int lane = tid & 63;
    const int mb   = (int)blockIdx.x >> 5;   // 0..7
    const int nb   = (int)blockIdx.x & 31;   // 0..31
    const int row0 = mb * 32;
    const int col0 = nb * 32;
    const int tr = lane >> 3;            // 0..7   (compute phase)
    const int tc = lane & 7;             // 0..7
    const int rr = tid >> 3;             // 0..31  (reduce phase)
    const int cc = (tid & 7) * 4;

    // diagonal of Wr for this thread's 4 output columns (constant across t)
    float wd[4];
    #pragma unroll
    for (int j = 0; j < 4; ++j)
        wd[j] = Wr[(size_t)(col0 + cc + j) * Uu + (col0 + cc + j)];

    const int rA = lane & 31;            // A staging row
    const int kA = lane >> 5;            // A staging k-float4 parity

    for (int t = 0; t < Tt; ++t) {
        const float* hbase  = (t == 0) ? h0 : (out + (size_t)(t - 1) * Uu);
        const size_t hstride = (t == 0) ? (size_t)Uu : (size_t)Tt * Uu;

        float acc[4][4] = {};
        const int kw = w * 256;
        #pragma unroll 1
        for (int c = 0; c < 4; ++c) {
            const int k0 = kw + c * 64;
            // stage A: h[row0..row0+31][k0..k0+63] -> As[w][k][r] (transposed)
            #pragma unroll
            for (int f = 0; f < 8; ++f) {
                const int k4 = kA + f * 2;    // 0..15
                float4 v = *reinterpret_cast<const float4*>(
                    &hbase[(size_t)(row0 + rA) * hstride + k0 + k4 * 4]);
                As[w][k4*4+0][rA] = v.x;
                As[w][k4*4+1][rA] = v.y;
                As[w][k4*4+2][rA] = v.z;
                As[w][k4*4+3][rA] = v.w;
            }
            // stage B: Wr[k0..k0+63][col0..col0+31] -> Bs[w][k][c]
            #pragma unroll
            for (int f = 0; f < 8; ++f) {
                const int fid = f * 64 + lane;
                const int kB  = fid >> 3;
                const int cB  = (fid & 7) * 4;
                *reinterpret_cast<float4*>(&Bs[w][kB][cB]) =
                    *reinterpret_cast<const float4*>(&Wr[(size_t)(k0 + kB) * Uu + col0 + cB]);
            }
            // wave-private: only lgkmcnt ordering needed (compiler inserts)
            #pragma unroll 4
            for (int kk = 0; kk < 64; ++kk) {
                float4 a = *reinterpret_cast<const float4*>(&As[w][kk][tr*4]);
                float4 b = *reinterpret_cast<const float4*>(&Bs[w][kk][tc*4]);
                float aa[4] = {a.x, a.y, a.z, a.w};
                float bb[4] = {b.x, b.y, b.z, b.w};
                #pragma unroll
                for (int i = 0; i < 4; ++i)
                    #pragma unroll
                    for (int j = 0; j < 4; ++j)
                        acc[i][j] += aa[i] * bb[j];
            }
        }

        // write this wave's 32x32 partial into its own As area
        float* Ps = &As[w][0][0];
        #pragma unroll
        for (int i = 0; i < 4; ++i) {
            float4 o;
            o.x = acc[i][0]; o.y = acc[i][1]; o.z = acc[i][2]; o.w = acc[i][3];
            *reinterpret_cast<float4*>(&Ps[(size_t)(tr*4 + i) * 32 + tc*4]) = o;
        }
        __syncthreads();

        // reduce 4 wave partials + xi + diagonal correction + pointwise
        float4 s = make_float4(0.f, 0.f, 0.f, 0.f);
        #pragma unroll
        for (int w2 = 0; w2 < 4; ++w2) {
            const float* Pw = &As[w2][0][0];
            float4 p = *reinterpret_cast<const float4*>(&Pw[(size_t)rr * 32 + cc]);
            s.x += p.x; s.y += p.y; s.z += p.z; s.w += p.w;
        }
        float* orow = &out[((size_t)(row0 + rr) * Tt + t) * Uu + col0 + cc];
        float4 xi = *reinterpret_cast<const float4*>(orow);
        float4 hd = *reinterpret_cast<const float4*>(
            &hbase[(size_t)(row0 + rr) * hstride + col0 + cc]);

        float iz[4];
        iz[0] = xi.x + s.x - hd.x * wd[0];
        iz[1] = xi.y + s.y - hd.y * wd[1];
        iz[2] = xi.z + s.z - hd.z * wd[2];
        iz[3] = xi.w + s.w - hd.w * wd[3];
        float4 o;
        float v0 = iz[0]*iz[0] - iz[0];
        float v1 = iz[1]*iz[1] - iz[1];
        float v2 = iz[2]*iz[2] - iz[2];
        float v3 = iz[3]*iz[3] - iz[3];
        o.x = fminf(fmaxf(v0, -1.f), 1.f);
        o.y = fminf(fmaxf(v1, -1.f), 1.f);
        o.z = fminf(fmaxf(v2, -1.f), 1.f);
        o.w = fminf(fmaxf(v3, -1.f), 1.f);
        *reinterpret_cast<float4*>(orow) = o;

        __threadfence();   // release: make out[:,t,:] visible device-wide
        grid.sync();
        __threadfence();   // acquire side for next step's h reads
    }
}

extern "C" void kernel_launch(void* const* d_in, const int* in_sizes, int n_in,
                              void* d_out, int out_size, void* d_ws, size_t ws_size,
                              hipStream_t stream) {
    const float* x  = (const float*)d_in[0];
    const float* h0 = (const float*)d_in[1];
    const float* Wi = (const float*)d_in[2];
    const float* b  = (const float*)d_in[3];
    const float* Wr = (const float*)d_in[4];
    float* out = (float*)d_out;

    // Phase 1: xi into d_out
    dim3 g1((Bb * Tt) / 64, Uu / 64);
    xi_gemm_kernel<<<g1, 256, 0, stream>>>(x, Wi, b, out);

    // Phase 2: cooperative scan (256 wgs = 1 per CU)
    void* args[] = { (void*)&Wr, (void*)&h0, (void*)&out };
    hipLaunchCooperativeKernel((const void*)scan_kernel, dim3(256), dim3(256),
                               args, 0, stream);
}

// Round 2
// 10602.235 us; speedup vs baseline: 1.0093x; 1.0093x over previous
//
#include <hip/hip_runtime.h>

#define Bb 256
#define Tt 128
#define Dd 512
#define Uu 1024

// ---------------- Kernel 1: xi = x @ W_i + b -> written into d_out[b][t][u] ----------
// M = B*T = 32768, K = D = 512, N = U = 1024.  BM=BN=64, BK=16, 256 thr, 4x4/thread.
__global__ __launch_bounds__(256, 1) void xi_gemm_kernel(
    const float* __restrict__ x, const float* __restrict__ Wi,
    const float* __restrict__ bias, float* __restrict__ out)
{
    __shared__ __align__(16) float As[16][64];   // [k][m]
    __shared__ __align__(16) float Bs[16][64];   // [k][n]
    const int tid  = threadIdx.x;
    const int row0 = blockIdx.x * 64;
    const int col0 = blockIdx.y * 64;
    const int tr = tid >> 4;       // 0..15
    const int tc = tid & 15;       // 0..15
    const int ra  = tid & 63;      // A row 0..63
    const int k4a = tid >> 6;      // A k-float4 0..3
    const int kb  = tid >> 4;      // B k row 0..15
    const int c4b = tid & 15;      // B col-float4 0..15

    float acc[4][4] = {};

    for (int k0 = 0; k0 < Dd; k0 += 16) {
        float4 av = *reinterpret_cast<const float4*>(&x[(size_t)(row0 + ra) * Dd + k0 + k4a * 4]);
        float4 bv = *reinterpret_cast<const float4*>(&Wi[(size_t)(k0 + kb) * Uu + col0 + c4b * 4]);
        __syncthreads();           // previous iter's LDS reads done
        As[k4a*4+0][ra] = av.x;
        As[k4a*4+1][ra] = av.y;
        As[k4a*4+2][ra] = av.z;
        As[k4a*4+3][ra] = av.w;
        *reinterpret_cast<float4*>(&Bs[kb][c4b*4]) = bv;
        __syncthreads();
        #pragma unroll
        for (int kk = 0; kk < 16; ++kk) {
            float4 a = *reinterpret_cast<const float4*>(&As[kk][tr*4]);
            float4 b = *reinterpret_cast<const float4*>(&Bs[kk][tc*4]);
            float aa[4] = {a.x, a.y, a.z, a.w};
            float bb[4] = {b.x, b.y, b.z, b.w};
            #pragma unroll
            for (int i = 0; i < 4; ++i)
                #pragma unroll
                for (int j = 0; j < 4; ++j)
                    acc[i][j] += aa[i] * bb[j];
        }
    }

    float4 bv = *reinterpret_cast<const float4*>(&bias[col0 + tc*4]);
    #pragma unroll
    for (int i = 0; i < 4; ++i) {
        float4 o;
        o.x = acc[i][0] + bv.x;  o.y = acc[i][1] + bv.y;
        o.z = acc[i][2] + bv.z;  o.w = acc[i][3] + bv.w;
        *reinterpret_cast<float4*>(&out[(size_t)(row0 + tr*4 + i) * Uu + col0 + tc*4]) = o;
    }
}

// ---------------- init: zero the group barrier counters (re-run every launch) ----------
__global__ void init_bar_kernel(unsigned* __restrict__ bar) {
    if (threadIdx.x < 32) bar[threadIdx.x * 64] = 0u;
}

// ---------------- Kernel 2: scan over T, group-local sync only ----------------
// 256 wgs = 32 groups x 8 members. Group g (= bid&31) owns samples [8g,8g+8);
// member c (= bid>>5) owns columns [128c,128c+128). With default round-robin
// dispatch (XCD = bid%8), all 8 members of a group share one XCD -> the
// per-step 8-way barrier and the h-state traffic stay XCD-L2-local.
// h history lives in d_out: step t reads out[:,t-1,:], writes out[:,t,:]
// (which also overwrites xi_t in place after consuming it).
__global__ __launch_bounds__(512, 2) void scan_kernel(
    const float* __restrict__ Wr, const float* __restrict__ h0,
    float* __restrict__ out, unsigned* __restrict__ bar)
{
    __shared__ __align__(16) float hs[8][1024];      // 32 KB: h rows of the 8 samples
    __shared__ __align__(16) float part[8][8][128];  // 32 KB: per-wave partials

    const int tid  = threadIdx.x;
    const int wv   = tid >> 6;          // wave 0..7
    const int lane = tid & 63;
    const int bid  = (int)blockIdx.x;
    const int g    = bid & 31;          // group (same XCD residue for all members)
    const int c    = bid >> 5;          // member / column slice
    const int b0   = g * 8;
    const int col0 = c * 128;

    // reduce-phase mapping: thread -> (sample rm, column pair ru)
    const int rm = tid >> 6;            // 0..7
    const int ru = (tid & 63) * 2;      // 0..126

    // diagonal of Wr for this thread's 2 output columns (constant across t)
    float2 wd;
    wd.x = Wr[(size_t)(col0 + ru)     * Uu + (col0 + ru)];
    wd.y = Wr[(size_t)(col0 + ru + 1) * Uu + (col0 + ru + 1)];

    const int k0w = wv * 128;           // this wave's K slice
    unsigned* cnt = bar + g * 64;       // 256B-spaced counters

    for (int t = 0; t < Tt; ++t) {
        // ---- stage h[8][1024] into LDS ----
        const float* hb;  size_t hstr;
        if (t == 0) { hb = h0 + (size_t)b0 * Uu;                  hstr = (size_t)Uu; }
        else        { hb = out + ((size_t)b0 * Tt + (t - 1)) * Uu; hstr = (size_t)Tt * Uu; }
        {
            const int sm = tid >> 6;         // sample
            const int c4 = (tid & 63) * 4;   // col base
            #pragma unroll
            for (int f = 0; f < 4; ++f) {
                const int col = c4 + f * 256;
                float4 v = *reinterpret_cast<const float4*>(&hb[(size_t)sm * hstr + col]);
                *reinterpret_cast<float4*>(&hs[sm][col]) = v;
            }
        }
        __syncthreads();

        // ---- GEMM: acc[m] (2 cols: 2*lane, 2*lane+1) over this wave's K=128 ----
        float2 acc[8];
        #pragma unroll
        for (int m = 0; m < 8; ++m) acc[m] = make_float2(0.f, 0.f);

        const float* wp = Wr + (size_t)k0w * Uu + col0 + 2 * lane;
        #pragma unroll 2
        for (int kk4 = 0; kk4 < 32; ++kk4) {
            float4 hv[8];
            #pragma unroll
            for (int m = 0; m < 8; ++m)
                hv[m] = *reinterpret_cast<const float4*>(&hs[m][k0w + kk4 * 4]);
            #pragma unroll
            for (int j = 0; j < 4; ++j) {
                float2 wvv = *reinterpret_cast<const float2*>(wp);
                wp += Uu;
                #pragma unroll
                for (int m = 0; m < 8; ++m) {
                    const float h = (j == 0) ? hv[m].x : (j == 1) ? hv[m].y
                                  : (j == 2) ? hv[m].z : hv[m].w;
                    acc[m].x = fmaf(h, wvv.x, acc[m].x);
                    acc[m].y = fmaf(h, wvv.y, acc[m].y);
                }
            }
        }

        // ---- partials to LDS ----
        #pragma unroll
        for (int m = 0; m < 8; ++m)
            *reinterpret_cast<float2*>(&part[wv][m][2 * lane]) = acc[m];
        __syncthreads();

        // ---- reduce 8 partials + xi + diag correction + pointwise + store ----
        float2 s = make_float2(0.f, 0.f);
        #pragma unroll
        for (int w2 = 0; w2 < 8; ++w2) {
            float2 p = *reinterpret_cast<const float2*>(&part[w2][rm][ru]);
            s.x += p.x;  s.y += p.y;
        }
        float* orow = &out[((size_t)(b0 + rm) * Tt + t) * Uu + col0 + ru];
        float2 xiv = *reinterpret_cast<const float2*>(orow);
        float2 hd  = *reinterpret_cast<const float2*>(&hs[rm][col0 + ru]);
        float iz0 = xiv.x + s.x - hd.x * wd.x;
        float iz1 = xiv.y + s.y - hd.y * wd.y;
        float v0 = iz0 * iz0 - iz0;
        float v1 = iz1 * iz1 - iz1;
        float2 o;
        o.x = fminf(fmaxf(v0, -1.f), 1.f);
        o.y = fminf(fmaxf(v1, -1.f), 1.f);
        *reinterpret_cast<float2*>(orow) = o;

        // ---- group-local barrier (8 members, XCD-local) ----
        __threadfence();                 // release our out[:,t,:] writes
        __syncthreads();                 // all waves' stores drained (vmcnt 0 at barrier)
        if (tid == 0) {
            __hip_atomic_fetch_add(cnt, 1u, __ATOMIC_RELEASE, __HIP_MEMORY_SCOPE_AGENT);
            const unsigned target = 8u * (unsigned)(t + 1);
            while (__hip_atomic_load(cnt, __ATOMIC_ACQUIRE, __HIP_MEMORY_SCOPE_AGENT) < target)
                __builtin_amdgcn_s_sleep(2);
        }
        __syncthreads();
        __threadfence();                 // acquire side for next step's h reads
    }
}

extern "C" void kernel_launch(void* const* d_in, const int* in_sizes, int n_in,
                              void* d_out, int out_size, void* d_ws, size_t ws_size,
                              hipStream_t stream) {
    const float* x  = (const float*)d_in[0];
    const float* h0 = (const float*)d_in[1];
    const float* Wi = (const float*)d_in[2];
    const float* b  = (const float*)d_in[3];
    const float* Wr = (const float*)d_in[4];
    float* out = (float*)d_out;
    unsigned* bar = (unsigned*)d_ws;     // 32 counters * 64 uints spacing = 8 KB

    // Phase 0: zero barrier counters (graph-replay safe)
    init_bar_kernel<<<1, 64, 0, stream>>>(bar);

    // Phase 1: xi into d_out
    dim3 g1((Bb * Tt) / 64, Uu / 64);
    xi_gemm_kernel<<<g1, 256, 0, stream>>>(x, Wi, b, out);

    // Phase 2: cooperative scan, 256 wgs x 512 threads (1 wg/CU, 2 waves/SIMD)
    void* args[] = { (void*)&Wr, (void*)&h0, (void*)&out, (void*)&bar };
    hipLaunchCooperativeKernel((const void*)scan_kernel, dim3(256), dim3(512),
                               args, 0, stream);
}

// Round 3
// 3385.082 us; speedup vs baseline: 3.1610x; 3.1320x over previous
//
#include <hip/hip_runtime.h>
#include <cstdint>

#define Bb 256
#define Tt 128
#define Dd 512
#define Uu 1024

// ---------------- Kernel 1: xi = x @ W_i + b -> written into d_out[b][t][u] ----------
__global__ __launch_bounds__(256, 1) void xi_gemm_kernel(
    const float* __restrict__ x, const float* __restrict__ Wi,
    const float* __restrict__ bias, float* __restrict__ out)
{
    __shared__ __align__(16) float As[16][64];   // [k][m]
    __shared__ __align__(16) float Bs[16][64];   // [k][n]
    const int tid  = threadIdx.x;
    const int row0 = blockIdx.x * 64;
    const int col0 = blockIdx.y * 64;
    const int tr = tid >> 4;
    const int tc = tid & 15;
    const int ra  = tid & 63;
    const int k4a = tid >> 6;
    const int kb  = tid >> 4;
    const int c4b = tid & 15;

    float acc[4][4] = {};

    for (int k0 = 0; k0 < Dd; k0 += 16) {
        float4 av = *reinterpret_cast<const float4*>(&x[(size_t)(row0 + ra) * Dd + k0 + k4a * 4]);
        float4 bv = *reinterpret_cast<const float4*>(&Wi[(size_t)(k0 + kb) * Uu + col0 + c4b * 4]);
        __syncthreads();
        As[k4a*4+0][ra] = av.x;
        As[k4a*4+1][ra] = av.y;
        As[k4a*4+2][ra] = av.z;
        As[k4a*4+3][ra] = av.w;
        *reinterpret_cast<float4*>(&Bs[kb][c4b*4]) = bv;
        __syncthreads();
        #pragma unroll
        for (int kk = 0; kk < 16; ++kk) {
            float4 a = *reinterpret_cast<const float4*>(&As[kk][tr*4]);
            float4 b = *reinterpret_cast<const float4*>(&Bs[kk][tc*4]);
            float aa[4] = {a.x, a.y, a.z, a.w};
            float bb[4] = {b.x, b.y, b.z, b.w};
            #pragma unroll
            for (int i = 0; i < 4; ++i)
                #pragma unroll
                for (int j = 0; j < 4; ++j)
                    acc[i][j] += aa[i] * bb[j];
        }
    }

    float4 bv = *reinterpret_cast<const float4*>(&bias[col0 + tc*4]);
    #pragma unroll
    for (int i = 0; i < 4; ++i) {
        float4 o;
        o.x = acc[i][0] + bv.x;  o.y = acc[i][1] + bv.y;
        o.z = acc[i][2] + bv.z;  o.w = acc[i][3] + bv.w;
        *reinterpret_cast<float4*>(&out[(size_t)(row0 + tr*4 + i) * Uu + col0 + tc*4]) = o;
    }
}

// ---------------- init: zero the group barrier counters (re-run every launch) ----------
__global__ void init_bar_kernel(unsigned* __restrict__ bar) {
    if (threadIdx.x < 32) bar[threadIdx.x * 64] = 0u;
}

// LLC-coherent (device-scope, fence-free) 8B load/store: relaxed agent atomics
// compile to global_load/store_dwordx2 sc0 sc1 — bypass L1/L2 to the device
// coherence point, NO buffer_inv / buffer_wbl2 emitted. Correct for cross-wg
// data regardless of XCD placement, and leaves L2 (holding Wr) untouched.
__device__ __forceinline__ float2 llc_load_f2(const float* p) {
    uint64_t u = __hip_atomic_load((const uint64_t*)p, __ATOMIC_RELAXED,
                                   __HIP_MEMORY_SCOPE_AGENT);
    return __builtin_bit_cast(float2, u);
}
__device__ __forceinline__ void llc_store_f2(float* p, float2 v) {
    __hip_atomic_store((uint64_t*)p, __builtin_bit_cast(uint64_t, v),
                       __ATOMIC_RELAXED, __HIP_MEMORY_SCOPE_AGENT);
}

// ---------------- Kernel 2: scan over T ----------------
// 256 wgs = 32 groups x 8 members; group owns 8 samples, member owns 128 cols.
// All cross-wg data (h state) moves via LLC-coherent ops; Wr via plain loads
// stays hot in per-XCD L2 (never invalidated: steady state has NO fences).
__global__ __launch_bounds__(512, 2) void scan_kernel(
    const float* __restrict__ Wr, const float* __restrict__ h0,
    float* __restrict__ out, unsigned* __restrict__ bar)
{
    __shared__ __align__(16) float hs[8][1024];      // 32 KB: h rows of the 8 samples
    __shared__ __align__(16) float part[8][8][128];  // 32 KB: per-wave partials

    const int tid  = threadIdx.x;
    const int wv   = tid >> 6;          // wave 0..7
    const int lane = tid & 63;
    const int bid  = (int)blockIdx.x;
    const int g    = bid & 31;          // group
    const int c    = bid >> 5;          // member / column slice
    const int b0   = g * 8;
    const int col0 = c * 128;

    const int rm = tid >> 6;            // reduce: sample
    const int ru = (tid & 63) * 2;      // reduce: column pair

    // diagonal of Wr for this thread's 2 output columns (constant across t)
    float2 wd;
    wd.x = Wr[(size_t)(col0 + ru)     * Uu + (col0 + ru)];
    wd.y = Wr[(size_t)(col0 + ru + 1) * Uu + (col0 + ru + 1)];

    const int k0w = wv * 128;           // this wave's K slice
    unsigned* cnt = bar + g * 64;       // 256B-spaced counters

    for (int t = 0; t < Tt; ++t) {
        // ---- stage h[8][1024] into LDS via LLC-coherent loads ----
        const float* hb;  size_t hstr;
        if (t == 0) { hb = h0 + (size_t)b0 * Uu;                   hstr = (size_t)Uu; }
        else        { hb = out + ((size_t)b0 * Tt + (t - 1)) * Uu; hstr = (size_t)Tt * Uu; }
        {
            const float* hrow = hb + (size_t)rm * hstr;   // wave rm stages sample rm
            #pragma unroll
            for (int f = 0; f < 8; ++f) {
                const int e2 = f * 64 + lane;             // float2 index 0..511
                float2 v = llc_load_f2(hrow + e2 * 2);
                *reinterpret_cast<float2*>(&hs[rm][e2 * 2]) = v;
            }
        }
        __syncthreads();

        // ---- GEMM: acc[m] (cols 2*lane, 2*lane+1) over this wave's K=128 ----
        float2 acc[8];
        #pragma unroll
        for (int m = 0; m < 8; ++m) acc[m] = make_float2(0.f, 0.f);

        const float* wp = Wr + (size_t)k0w * Uu + col0 + 2 * lane;
        #pragma unroll 4
        for (int kk4 = 0; kk4 < 32; ++kk4) {
            float4 hv[8];
            #pragma unroll
            for (int m = 0; m < 8; ++m)
                hv[m] = *reinterpret_cast<const float4*>(&hs[m][k0w + kk4 * 4]);
            #pragma unroll
            for (int j = 0; j < 4; ++j) {
                float2 wvv = *reinterpret_cast<const float2*>(wp);
                wp += Uu;
                #pragma unroll
                for (int m = 0; m < 8; ++m) {
                    const float h = (j == 0) ? hv[m].x : (j == 1) ? hv[m].y
                                  : (j == 2) ? hv[m].z : hv[m].w;
                    acc[m].x = fmaf(h, wvv.x, acc[m].x);
                    acc[m].y = fmaf(h, wvv.y, acc[m].y);
                }
            }
        }

        // ---- partials to LDS ----
        #pragma unroll
        for (int m = 0; m < 8; ++m)
            *reinterpret_cast<float2*>(&part[wv][m][2 * lane]) = acc[m];
        __syncthreads();

        // ---- reduce 8 partials + xi + diag correction + pointwise + store ----
        float2 s = make_float2(0.f, 0.f);
        #pragma unroll
        for (int w2 = 0; w2 < 8; ++w2) {
            float2 p = *reinterpret_cast<const float2*>(&part[w2][rm][ru]);
            s.x += p.x;  s.y += p.y;
        }
        float* orow = &out[((size_t)(b0 + rm) * Tt + t) * Uu + col0 + ru];
        // xi: written by xi_gemm (pre-kernel), only ever touched by this thread
        // within this kernel -> plain nontemporal load (don't pollute L2/Wr).
        float2 xiv = __builtin_bit_cast(float2,
            __builtin_nontemporal_load(reinterpret_cast<const uint64_t*>(orow)));
        float2 hd  = *reinterpret_cast<const float2*>(&hs[rm][col0 + ru]);
        float iz0 = xiv.x + s.x - hd.x * wd.x;
        float iz1 = xiv.y + s.y - hd.y * wd.y;
        float v0 = iz0 * iz0 - iz0;
        float v1 = iz1 * iz1 - iz1;
        float2 o;
        o.x = fminf(fmaxf(v0, -1.f), 1.f);
        o.y = fminf(fmaxf(v1, -1.f), 1.f);
        llc_store_f2(orow, o);           // LLC-coherent: next step's readers see it

        // ---- group barrier: relaxed monotonic counter, no fences ----
        // __syncthreads drains each wave's vmcnt(0) -> all llc stores are at the
        // coherence point before tid0 signals.
        __syncthreads();
        if (tid == 0) {
            __hip_atomic_fetch_add(cnt, 1u, __ATOMIC_RELAXED, __HIP_MEMORY_SCOPE_AGENT);
            const unsigned target = 8u * (unsigned)(t + 1);
            while (__hip_atomic_load(cnt, __ATOMIC_RELAXED, __HIP_MEMORY_SCOPE_AGENT) < target)
                __builtin_amdgcn_s_sleep(4);
        }
        __syncthreads();
    }
}

extern "C" void kernel_launch(void* const* d_in, const int* in_sizes, int n_in,
                              void* d_out, int out_size, void* d_ws, size_t ws_size,
                              hipStream_t stream) {
    const float* x  = (const float*)d_in[0];
    const float* h0 = (const float*)d_in[1];
    const float* Wi = (const float*)d_in[2];
    const float* b  = (const float*)d_in[3];
    const float* Wr = (const float*)d_in[4];
    float* out = (float*)d_out;
    unsigned* bar = (unsigned*)d_ws;     // 32 counters * 256B spacing = 8 KB

    init_bar_kernel<<<1, 64, 0, stream>>>(bar);

    dim3 g1((Bb * Tt) / 64, Uu / 64);
    xi_gemm_kernel<<<g1, 256, 0, stream>>>(x, Wi, b, out);

    void* args[] = { (void*)&Wr, (void*)&h0, (void*)&out, (void*)&bar };
    hipLaunchCooperativeKernel((const void*)scan_kernel, dim3(256), dim3(512),
                               args, 0, stream);
}

// Round 4
// 2503.910 us; speedup vs baseline: 4.2735x; 1.3519x over previous
//
#include <hip/hip_runtime.h>
#include <cstdint>

#define Bb 256
#define Tt 128
#define Dd 512
#define Uu 1024

// ---------------- Kernel 1: xi = x @ W_i + b -> written into d_out[b][t][u] ----------
__global__ __launch_bounds__(256, 1) void xi_gemm_kernel(
    const float* __restrict__ x, const float* __restrict__ Wi,
    const float* __restrict__ bias, float* __restrict__ out)
{
    __shared__ __align__(16) float As[16][64];   // [k][m]
    __shared__ __align__(16) float Bs[16][64];   // [k][n]
    const int tid  = threadIdx.x;
    const int row0 = blockIdx.x * 64;
    const int col0 = blockIdx.y * 64;
    const int tr = tid >> 4;
    const int tc = tid & 15;
    const int ra  = tid & 63;
    const int k4a = tid >> 6;
    const int kb  = tid >> 4;
    const int c4b = tid & 15;

    float acc[4][4] = {};

    for (int k0 = 0; k0 < Dd; k0 += 16) {
        float4 av = *reinterpret_cast<const float4*>(&x[(size_t)(row0 + ra) * Dd + k0 + k4a * 4]);
        float4 bv = *reinterpret_cast<const float4*>(&Wi[(size_t)(k0 + kb) * Uu + col0 + c4b * 4]);
        __syncthreads();
        As[k4a*4+0][ra] = av.x;
        As[k4a*4+1][ra] = av.y;
        As[k4a*4+2][ra] = av.z;
        As[k4a*4+3][ra] = av.w;
        *reinterpret_cast<float4*>(&Bs[kb][c4b*4]) = bv;
        __syncthreads();
        #pragma unroll
        for (int kk = 0; kk < 16; ++kk) {
            float4 a = *reinterpret_cast<const float4*>(&As[kk][tr*4]);
            float4 b = *reinterpret_cast<const float4*>(&Bs[kk][tc*4]);
            float aa[4] = {a.x, a.y, a.z, a.w};
            float bb[4] = {b.x, b.y, b.z, b.w};
            #pragma unroll
            for (int i = 0; i < 4; ++i)
                #pragma unroll
                for (int j = 0; j < 4; ++j)
                    acc[i][j] += aa[i] * bb[j];
        }
    }

    float4 bv = *reinterpret_cast<const float4*>(&bias[col0 + tc*4]);
    #pragma unroll
    for (int i = 0; i < 4; ++i) {
        float4 o;
        o.x = acc[i][0] + bv.x;  o.y = acc[i][1] + bv.y;
        o.z = acc[i][2] + bv.z;  o.w = acc[i][3] + bv.w;
        *reinterpret_cast<float4*>(&out[(size_t)(row0 + tr*4 + i) * Uu + col0 + tc*4]) = o;
    }
}

// ---------------- init: zero the group barrier counters (re-run every launch) ----------
__global__ void init_bar_kernel(unsigned* __restrict__ bar) {
    if (threadIdx.x < 32) bar[threadIdx.x * 64] = 0u;
}

// LLC-coherent (device-scope, fence-free) 8B load/store: relaxed agent atomics
// compile to global_load/store_dwordx2 sc0 sc1 — bypass L1/L2 to the device
// coherence point, NO buffer_inv / buffer_wbl2. Leaves L2 (holding Wr) intact.
__device__ __forceinline__ float2 llc_load_f2(const float* p) {
    uint64_t u = __hip_atomic_load((const uint64_t*)p, __ATOMIC_RELAXED,
                                   __HIP_MEMORY_SCOPE_AGENT);
    return __builtin_bit_cast(float2, u);
}
__device__ __forceinline__ void llc_store_f2(float* p, float2 v) {
    __hip_atomic_store((uint64_t*)p, __builtin_bit_cast(uint64_t, v),
                       __ATOMIC_RELAXED, __HIP_MEMORY_SCOPE_AGENT);
}

// ---------------- Kernel 2: scan over T ----------------
// 256 wgs = 32 groups x 8 members; group owns 8 samples, member owns 128 cols.
// XCD SHARDING (the round-4 change): member c = bid&7 -> with round-robin
// dispatch XCD = bid%8 = c, so every wg resident on XCD x streams the SAME
// 512 KB slab Wr[:, 128x..128x+128) -> slab stays hot in the 4 MB per-XCD L2
// (previous mapping put the full 4 MB Wr on every XCD = capacity thrash).
// Cross-wg data (h state, barrier) moves via LLC ops — XCD-agnostic, proven
// in rounds 2/3 to cost the same regardless of member placement.
__global__ __launch_bounds__(512, 2) void scan_kernel(
    const float* __restrict__ Wr, const float* __restrict__ h0,
    float* __restrict__ out, unsigned* __restrict__ bar)
{
    __shared__ __align__(16) float hs[8][1024];      // 32 KB: h rows of the 8 samples
    __shared__ __align__(16) float part[8][8][128];  // 32 KB: per-wave partials

    const int tid  = threadIdx.x;
    const int wv   = tid >> 6;          // wave 0..7
    const int lane = tid & 63;
    const int bid  = (int)blockIdx.x;
    const int g    = bid >> 3;          // group 0..31
    const int c    = bid & 7;           // member / column slice == XCD id
    const int b0   = g * 8;
    const int col0 = c * 128;

    const int rm = tid >> 6;            // reduce: sample
    const int ru = (tid & 63) * 2;      // reduce: column pair

    // diagonal of Wr for this thread's 2 output columns (constant across t)
    float2 wd;
    wd.x = Wr[(size_t)(col0 + ru)     * Uu + (col0 + ru)];
    wd.y = Wr[(size_t)(col0 + ru + 1) * Uu + (col0 + ru + 1)];

    const int k0w = wv * 128;           // this wave's K slice
    unsigned* cnt = bar + g * 64;       // 256B-spaced counters

    for (int t = 0; t < Tt; ++t) {
        // ---- stage h[8][1024] into LDS via LLC-coherent loads ----
        const float* hb;  size_t hstr;
        if (t == 0) { hb = h0 + (size_t)b0 * Uu;                   hstr = (size_t)Uu; }
        else        { hb = out + ((size_t)b0 * Tt + (t - 1)) * Uu; hstr = (size_t)Tt * Uu; }
        {
            const float* hrow = hb + (size_t)rm * hstr;   // wave rm stages sample rm
            #pragma unroll
            for (int f = 0; f < 8; ++f) {
                const int e2 = f * 64 + lane;             // float2 index 0..511
                float2 v = llc_load_f2(hrow + e2 * 2);
                *reinterpret_cast<float2*>(&hs[rm][e2 * 2]) = v;
            }
        }
        // xi for this thread's output element: issue EARLY (independent of h),
        // ~700cy L3 latency hides under the GEMM below. Plain nontemporal load
        // is safe: this exact address is only ever read+written by this thread.
        float* orow = &out[((size_t)(b0 + rm) * Tt + t) * Uu + col0 + ru];
        float2 xiv = __builtin_bit_cast(float2,
            __builtin_nontemporal_load(reinterpret_cast<const uint64_t*>(orow)));
        __syncthreads();

        // ---- GEMM: acc[m] (cols 2*lane, 2*lane+1) over this wave's K=128 ----
        float2 acc[8];
        #pragma unroll
        for (int m = 0; m < 8; ++m) acc[m] = make_float2(0.f, 0.f);

        const float* wp = Wr + (size_t)k0w * Uu + col0 + 2 * lane;
        #pragma unroll 8
        for (int kk4 = 0; kk4 < 32; ++kk4) {
            float4 hv[8];
            #pragma unroll
            for (int m = 0; m < 8; ++m)
                hv[m] = *reinterpret_cast<const float4*>(&hs[m][k0w + kk4 * 4]);
            #pragma unroll
            for (int j = 0; j < 4; ++j) {
                float2 wvv = *reinterpret_cast<const float2*>(wp);
                wp += Uu;
                #pragma unroll
                for (int m = 0; m < 8; ++m) {
                    const float h = (j == 0) ? hv[m].x : (j == 1) ? hv[m].y
                                  : (j == 2) ? hv[m].z : hv[m].w;
                    acc[m].x = fmaf(h, wvv.x, acc[m].x);
                    acc[m].y = fmaf(h, wvv.y, acc[m].y);
                }
            }
        }

        // ---- partials to LDS ----
        #pragma unroll
        for (int m = 0; m < 8; ++m)
            *reinterpret_cast<float2*>(&part[wv][m][2 * lane]) = acc[m];
        __syncthreads();

        // ---- reduce 8 partials + xi + diag correction + pointwise + store ----
        float2 s = make_float2(0.f, 0.f);
        #pragma unroll
        for (int w2 = 0; w2 < 8; ++w2) {
            float2 p = *reinterpret_cast<const float2*>(&part[w2][rm][ru]);
            s.x += p.x;  s.y += p.y;
        }
        float2 hd  = *reinterpret_cast<const float2*>(&hs[rm][col0 + ru]);
        float iz0 = xiv.x + s.x - hd.x * wd.x;
        float iz1 = xiv.y + s.y - hd.y * wd.y;
        float v0 = iz0 * iz0 - iz0;
        float v1 = iz1 * iz1 - iz1;
        float2 o;
        o.x = fminf(fmaxf(v0, -1.f), 1.f);
        o.y = fminf(fmaxf(v1, -1.f), 1.f);
        llc_store_f2(orow, o);           // LLC-coherent: next step's readers see it

        // ---- group barrier: relaxed monotonic counter, no fences ----
        // __syncthreads drains each wave's vmcnt(0) -> all llc stores are at the
        // coherence point before tid0 signals.
        __syncthreads();
        if (tid == 0) {
            __hip_atomic_fetch_add(cnt, 1u, __ATOMIC_RELAXED, __HIP_MEMORY_SCOPE_AGENT);
            const unsigned target = 8u * (unsigned)(t + 1);
            while (__hip_atomic_load(cnt, __ATOMIC_RELAXED, __HIP_MEMORY_SCOPE_AGENT) < target)
                __builtin_amdgcn_s_sleep(4);
        }
        __syncthreads();
    }
}

extern "C" void kernel_launch(void* const* d_in, const int* in_sizes, int n_in,
                              void* d_out, int out_size, void* d_ws, size_t ws_size,
                              hipStream_t stream) {
    const float* x  = (const float*)d_in[0];
    const float* h0 = (const float*)d_in[1];
    const float* Wi = (const float*)d_in[2];
    const float* b  = (const float*)d_in[3];
    const float* Wr = (const float*)d_in[4];
    float* out = (float*)d_out;
    unsigned* bar = (unsigned*)d_ws;     // 32 counters * 256B spacing = 8 KB

    init_bar_kernel<<<1, 64, 0, stream>>>(bar);

    dim3 g1((Bb * Tt) / 64, Uu / 64);
    xi_gemm_kernel<<<g1, 256, 0, stream>>>(x, Wi, b, out);

    void* args[] = { (void*)&Wr, (void*)&h0, (void*)&out, (void*)&bar };
    hipLaunchCooperativeKernel((const void*)scan_kernel, dim3(256), dim3(512),
                               args, 0, stream);
}

// Round 5
// 1894.947 us; speedup vs baseline: 5.6468x; 1.3214x over previous
//
#include <hip/hip_runtime.h>
#include <cstdint>

#define Bb 256
#define Tt 128
#define Dd 512
#define Uu 1024

// ---------------- Kernel 1: xi = x @ W_i + b -> written into d_out[b][t][u] ----------
__global__ __launch_bounds__(256, 1) void xi_gemm_kernel(
    const float* __restrict__ x, const float* __restrict__ Wi,
    const float* __restrict__ bias, float* __restrict__ out)
{
    __shared__ __align__(16) float As[16][64];   // [k][m]
    __shared__ __align__(16) float Bs[16][64];   // [k][n]
    const int tid  = threadIdx.x;
    const int row0 = blockIdx.x * 64;
    const int col0 = blockIdx.y * 64;
    const int tr = tid >> 4;
    const int tc = tid & 15;
    const int ra  = tid & 63;
    const int k4a = tid >> 6;
    const int kb  = tid >> 4;
    const int c4b = tid & 15;

    float acc[4][4] = {};

    for (int k0 = 0; k0 < Dd; k0 += 16) {
        float4 av = *reinterpret_cast<const float4*>(&x[(size_t)(row0 + ra) * Dd + k0 + k4a * 4]);
        float4 bv = *reinterpret_cast<const float4*>(&Wi[(size_t)(k0 + kb) * Uu + col0 + c4b * 4]);
        __syncthreads();
        As[k4a*4+0][ra] = av.x;
        As[k4a*4+1][ra] = av.y;
        As[k4a*4+2][ra] = av.z;
        As[k4a*4+3][ra] = av.w;
        *reinterpret_cast<float4*>(&Bs[kb][c4b*4]) = bv;
        __syncthreads();
        #pragma unroll
        for (int kk = 0; kk < 16; ++kk) {
            float4 a = *reinterpret_cast<const float4*>(&As[kk][tr*4]);
            float4 b = *reinterpret_cast<const float4*>(&Bs[kk][tc*4]);
            float aa[4] = {a.x, a.y, a.z, a.w};
            float bb[4] = {b.x, b.y, b.z, b.w};
            #pragma unroll
            for (int i = 0; i < 4; ++i)
                #pragma unroll
                for (int j = 0; j < 4; ++j)
                    acc[i][j] += aa[i] * bb[j];
        }
    }

    float4 bv = *reinterpret_cast<const float4*>(&bias[col0 + tc*4]);
    #pragma unroll
    for (int i = 0; i < 4; ++i) {
        float4 o;
        o.x = acc[i][0] + bv.x;  o.y = acc[i][1] + bv.y;
        o.z = acc[i][2] + bv.z;  o.w = acc[i][3] + bv.w;
        *reinterpret_cast<float4*>(&out[(size_t)(row0 + tr*4 + i) * Uu + col0 + tc*4]) = o;
    }
}

// ---------------- init: zero the group barrier counters (re-run every launch) ----------
__global__ void init_bar_kernel(unsigned* __restrict__ bar) {
    if (threadIdx.x < 32) bar[threadIdx.x * 64] = 0u;
}

// LLC-coherent (device-scope, fence-free) 8B load/store: relaxed agent atomics ->
// global_load/store_dwordx2 sc0 sc1. No buffer_inv/wbl2; L2 (holding Wr) untouched.
__device__ __forceinline__ float2 llc_load_f2(const float* p) {
    uint64_t u = __hip_atomic_load((const uint64_t*)p, __ATOMIC_RELAXED,
                                   __HIP_MEMORY_SCOPE_AGENT);
    return __builtin_bit_cast(float2, u);
}
__device__ __forceinline__ void llc_store_f2(float* p, float2 v) {
    __hip_atomic_store((uint64_t*)p, __builtin_bit_cast(uint64_t, v),
                       __ATOMIC_RELAXED, __HIP_MEMORY_SCOPE_AGENT);
}

// hs slot swizzle: physical 16B-slot = slot ^ ((slot>>3)&3).
// GEMM reader's 4 lane-subgroups (slot bits[4:3]) land on distinct slot%8 ->
// disjoint bank quads -> conflict-free 4-address broadcast reads.
__device__ __forceinline__ int swz_slot(int slot) { return slot ^ ((slot >> 3) & 3); }

// ---------------- Kernel 2: scan over T ----------------
// 256 wgs = 32 groups x 8 members; group g=bid>>3 owns samples [8g,8g+8);
// member c=bid&7 (== XCD with round-robin dispatch) owns cols [128c,128c+128)
// -> each XCD streams only its 512 KB Wr slab (L2-resident).
// Round-5 restructure: lane owns 8 cols; 4 lane-subgroups split the wave's
// K=128 -> h broadcasts drop 256->64 per wave/step; Wr loads are batched
// float4; subgroup partials folded by shfl_xor butterflies.
__global__ __launch_bounds__(512, 2) void scan_kernel(
    const float* __restrict__ Wr, const float* __restrict__ h0,
    float* __restrict__ out, unsigned* __restrict__ bar)
{
    __shared__ __align__(16) float hs[8][1024];      // 32 KB, slot-swizzled
    __shared__ __align__(16) float part[8][8][128];  // 32 KB: per-wave partials

    const int tid  = threadIdx.x;
    const int wv   = tid >> 6;          // wave 0..7
    const int lane = tid & 63;
    const int bid  = (int)blockIdx.x;
    const int g    = bid >> 3;          // group 0..31
    const int c    = bid & 7;           // member / column slice == XCD id
    const int b0   = g * 8;
    const int col0 = c * 128;

    const int cl = lane & 15;           // col block within slice (8 cols)
    const int q  = lane >> 4;           // k subgroup 0..3
    const int c0 = col0 + cl * 8;
    const int kb0 = wv * 128 + q * 32;  // this lane's K base (K=32)

    const int rm = tid >> 6;            // reduce: sample
    const int ru = (tid & 63) * 2;      // reduce: column pair

    // diagonal of Wr for this thread's 2 output columns (constant across t)
    float2 wd;
    wd.x = Wr[(size_t)(col0 + ru)     * Uu + (col0 + ru)];
    wd.y = Wr[(size_t)(col0 + ru + 1) * Uu + (col0 + ru + 1)];

    unsigned* cnt = bar + g * 64;       // 256B-spaced counters

    for (int t = 0; t < Tt; ++t) {
        // ---- stage h[8][1024] into swizzled LDS via LLC loads (wave wv -> sample wv) ----
        const float* hb;  size_t hstr;
        if (t == 0) { hb = h0 + (size_t)b0 * Uu;                   hstr = (size_t)Uu; }
        else        { hb = out + ((size_t)b0 * Tt + (t - 1)) * Uu; hstr = (size_t)Tt * Uu; }
        {
            const float* hrow = hb + (size_t)wv * hstr;
            #pragma unroll
            for (int f = 0; f < 4; ++f) {
                const int slot = f * 64 + lane;        // 16B slot 0..255
                const int col  = slot * 4;
                float2 v0 = llc_load_f2(hrow + col);
                float2 v1 = llc_load_f2(hrow + col + 2);
                float4 w;  w.x = v0.x; w.y = v0.y; w.z = v1.x; w.w = v1.y;
                *reinterpret_cast<float4*>(&hs[wv][swz_slot(slot) * 4]) = w;
            }
        }
        // xi for this thread's output element: issue EARLY, hides under GEMM.
        float* orow = &out[((size_t)(b0 + rm) * Tt + t) * Uu + col0 + ru];
        float2 xiv = __builtin_bit_cast(float2,
            __builtin_nontemporal_load(reinterpret_cast<const uint64_t*>(orow)));
        __syncthreads();

        // ---- GEMM: acc[m][8 cols] over this lane's K=32 ----
        float4 acc0[8], acc1[8];
        #pragma unroll
        for (int m = 0; m < 8; ++m) {
            acc0[m] = make_float4(0.f, 0.f, 0.f, 0.f);
            acc1[m] = make_float4(0.f, 0.f, 0.f, 0.f);
        }

        const float* wrp = Wr + (size_t)kb0 * Uu + c0;
        #pragma unroll 2
        for (int it = 0; it < 8; ++it) {           // 4 k per iteration
            const int slot = (kb0 >> 2) + it;      // = wv*32 + q*8 + it
            // batched Wr loads: 8x float4 in flight
            float4 w0[4], w1[4];
            #pragma unroll
            for (int j = 0; j < 4; ++j) {
                const float* r = wrp + (size_t)(it * 4 + j) * Uu;
                w0[j] = *reinterpret_cast<const float4*>(r);
                w1[j] = *reinterpret_cast<const float4*>(r + 4);
            }
            // h broadcast: 8x b128, 4 distinct swizzled slots (conflict-free)
            float4 hv[8];
            #pragma unroll
            for (int m = 0; m < 8; ++m)
                hv[m] = *reinterpret_cast<const float4*>(&hs[m][swz_slot(slot) * 4]);
            #pragma unroll
            for (int j = 0; j < 4; ++j) {
                #pragma unroll
                for (int m = 0; m < 8; ++m) {
                    const float h = (j == 0) ? hv[m].x : (j == 1) ? hv[m].y
                                  : (j == 2) ? hv[m].z : hv[m].w;
                    acc0[m].x = fmaf(h, w0[j].x, acc0[m].x);
                    acc0[m].y = fmaf(h, w0[j].y, acc0[m].y);
                    acc0[m].z = fmaf(h, w0[j].z, acc0[m].z);
                    acc0[m].w = fmaf(h, w0[j].w, acc0[m].w);
                    acc1[m].x = fmaf(h, w1[j].x, acc1[m].x);
                    acc1[m].y = fmaf(h, w1[j].y, acc1[m].y);
                    acc1[m].z = fmaf(h, w1[j].z, acc1[m].z);
                    acc1[m].w = fmaf(h, w1[j].w, acc1[m].w);
                }
            }
        }

        // ---- fold the 4 k-subgroups: butterflies over lane bits 4,5 ----
        #pragma unroll
        for (int m = 0; m < 8; ++m) {
            float* a = reinterpret_cast<float*>(&acc0[m]);
            float* b = reinterpret_cast<float*>(&acc1[m]);
            #pragma unroll
            for (int e = 0; e < 4; ++e) {
                a[e] += __shfl_xor(a[e], 16);
                a[e] += __shfl_xor(a[e], 32);
                b[e] += __shfl_xor(b[e], 16);
                b[e] += __shfl_xor(b[e], 32);
            }
        }
        // lanes of subgroup 0 write this wave's 8x128 partial
        if (q == 0) {
            #pragma unroll
            for (int m = 0; m < 8; ++m) {
                *reinterpret_cast<float4*>(&part[wv][m][cl * 8])     = acc0[m];
                *reinterpret_cast<float4*>(&part[wv][m][cl * 8 + 4]) = acc1[m];
            }
        }
        __syncthreads();

        // ---- reduce 8 wave partials + xi + diag correction + pointwise + store ----
        float2 s = make_float2(0.f, 0.f);
        #pragma unroll
        for (int w2 = 0; w2 < 8; ++w2) {
            float2 p = *reinterpret_cast<const float2*>(&part[w2][rm][ru]);
            s.x += p.x;  s.y += p.y;
        }
        // h(t-1) for diag correction: read through the swizzle
        const int hc   = col0 + ru;
        const int hsl  = hc >> 2;
        const float* hdp = &hs[rm][swz_slot(hsl) * 4 + (hc & 3)];
        float2 hd = *reinterpret_cast<const float2*>(hdp);

        float iz0 = xiv.x + s.x - hd.x * wd.x;
        float iz1 = xiv.y + s.y - hd.y * wd.y;
        float v0 = iz0 * iz0 - iz0;
        float v1 = iz1 * iz1 - iz1;
        float2 o;
        o.x = fminf(fmaxf(v0, -1.f), 1.f);
        o.y = fminf(fmaxf(v1, -1.f), 1.f);
        llc_store_f2(orow, o);

        // ---- group barrier: relaxed monotonic counter, no fences ----
        __syncthreads();                 // drains vmcnt(0): llc stores at LLC
        if (tid == 0) {
            __hip_atomic_fetch_add(cnt, 1u, __ATOMIC_RELAXED, __HIP_MEMORY_SCOPE_AGENT);
            const unsigned target = 8u * (unsigned)(t + 1);
            while (__hip_atomic_load(cnt, __ATOMIC_RELAXED, __HIP_MEMORY_SCOPE_AGENT) < target)
                __builtin_amdgcn_s_sleep(2);
        }
        __syncthreads();
    }
}

extern "C" void kernel_launch(void* const* d_in, const int* in_sizes, int n_in,
                              void* d_out, int out_size, void* d_ws, size_t ws_size,
                              hipStream_t stream) {
    const float* x  = (const float*)d_in[0];
    const float* h0 = (const float*)d_in[1];
    const float* Wi = (const float*)d_in[2];
    const float* b  = (const float*)d_in[3];
    const float* Wr = (const float*)d_in[4];
    float* out = (float*)d_out;
    unsigned* bar = (unsigned*)d_ws;     // 32 counters * 256B spacing = 8 KB

    init_bar_kernel<<<1, 64, 0, stream>>>(bar);

    dim3 g1((Bb * Tt) / 64, Uu / 64);
    xi_gemm_kernel<<<g1, 256, 0, stream>>>(x, Wi, b, out);

    void* args[] = { (void*)&Wr, (void*)&h0, (void*)&out, (void*)&bar };
    hipLaunchCooperativeKernel((const void*)scan_kernel, dim3(256), dim3(512),
                               args, 0, stream);
}

// Round 8
// 1776.193 us; speedup vs baseline: 6.0243x; 1.0669x over previous
//
#include <hip/hip_runtime.h>
#include <hip/hip_bf16.h>
#include <cstdint>

#define Bb 256
#define Tt 128
#define Dd 512
#define Uu 1024

typedef __attribute__((ext_vector_type(8))) short short8v;  // 8 bf16 = 4 VGPRs
typedef __attribute__((ext_vector_type(4))) float f32x4;

// ---------------- Kernel 1: xi = x @ W_i + b -> d_out[b][t][u] (f32 VALU, unchanged) ----
__global__ __launch_bounds__(256, 1) void xi_gemm_kernel(
    const float* __restrict__ x, const float* __restrict__ Wi,
    const float* __restrict__ bias, float* __restrict__ out)
{
    __shared__ __align__(16) float As[16][64];   // [k][m]
    __shared__ __align__(16) float Bs[16][64];   // [k][n]
    const int tid  = threadIdx.x;
    const int row0 = blockIdx.x * 64;
    const int col0 = blockIdx.y * 64;
    const int tr = tid >> 4;
    const int tc = tid & 15;
    const int ra  = tid & 63;
    const int k4a = tid >> 6;
    const int kb  = tid >> 4;
    const int c4b = tid & 15;

    float acc[4][4] = {};

    for (int k0 = 0; k0 < Dd; k0 += 16) {
        float4 av = *reinterpret_cast<const float4*>(&x[(size_t)(row0 + ra) * Dd + k0 + k4a * 4]);
        float4 bv = *reinterpret_cast<const float4*>(&Wi[(size_t)(k0 + kb) * Uu + col0 + c4b * 4]);
        __syncthreads();
        As[k4a*4+0][ra] = av.x;
        As[k4a*4+1][ra] = av.y;
        As[k4a*4+2][ra] = av.z;
        As[k4a*4+3][ra] = av.w;
        *reinterpret_cast<float4*>(&Bs[kb][c4b*4]) = bv;
        __syncthreads();
        #pragma unroll
        for (int kk = 0; kk < 16; ++kk) {
            float4 a = *reinterpret_cast<const float4*>(&As[kk][tr*4]);
            float4 b = *reinterpret_cast<const float4*>(&Bs[kk][tc*4]);
            float aa[4] = {a.x, a.y, a.z, a.w};
            float bb[4] = {b.x, b.y, b.z, b.w};
            #pragma unroll
            for (int i = 0; i < 4; ++i)
                #pragma unroll
                for (int j = 0; j < 4; ++j)
                    acc[i][j] += aa[i] * bb[j];
        }
    }

    float4 bv = *reinterpret_cast<const float4*>(&bias[col0 + tc*4]);
    #pragma unroll
    for (int i = 0; i < 4; ++i) {
        float4 o;
        o.x = acc[i][0] + bv.x;  o.y = acc[i][1] + bv.y;
        o.z = acc[i][2] + bv.z;  o.w = acc[i][3] + bv.w;
        *reinterpret_cast<float4*>(&out[(size_t)(row0 + tr*4 + i) * Uu + col0 + tc*4]) = o;
    }
}

// ---------------- init: zero barrier counters ----------------
__global__ void init_bar_kernel(unsigned* __restrict__ bar) {
    if (threadIdx.x < 32) bar[threadIdx.x * 64] = 0u;
}

// LLC-coherent (fence-free device-scope) primitives: relaxed agent atomics ->
// global ops with sc0 sc1 (bypass L1/L2, no buffer_inv) — cross-XCD correct,
// leave per-XCD L2 untouched.
__device__ __forceinline__ uint64_t llc_load_u64(const void* p) {
    return __hip_atomic_load((const uint64_t*)p, __ATOMIC_RELAXED,
                             __HIP_MEMORY_SCOPE_AGENT);
}
__device__ __forceinline__ void llc_store_f2(float* p, float2 v) {
    __hip_atomic_store((uint64_t*)p, __builtin_bit_cast(uint64_t, v),
                       __ATOMIC_RELAXED, __HIP_MEMORY_SCOPE_AGENT);
}

__device__ __forceinline__ uint16_t f2bf_bits(float x) {
    union { __hip_bfloat16 h; uint16_t u; } c;
    c.h = __float2bfloat16(x);
    return c.u;
}
__device__ __forceinline__ float bfbits2f(uint16_t b) {
    uint32_t u = ((uint32_t)b) << 16;
    return __builtin_bit_cast(float, u);
}
// split x,y into packed-bf16 hi word and lo (residual) word
__device__ __forceinline__ void split2(float x, float y, uint32_t& hi, uint32_t& lo) {
    const uint16_t hx = f2bf_bits(x), hy = f2bf_bits(y);
    const uint16_t lx = f2bf_bits(x - bfbits2f(hx));
    const uint16_t ly = f2bf_bits(y - bfbits2f(hy));
    hi = (uint32_t)hx | ((uint32_t)hy << 16);
    lo = (uint32_t)lx | ((uint32_t)ly << 16);
}

// ---------------- Kernel 2: scan over T — split-bf16 MFMA, Wr register-resident ----
// 256 wgs = 16 groups x 16 members. Group g owns samples [16g,16g+16);
// member owns 64 cols. Wave w: col-tile ct=w>>1 (16 cols), K-half kh=w&1 (512).
// Wr tile lives in registers as TWO bf16 fragments sets (hi + lo residual),
// 128 VGPRs, loaded once, diag zeroed.  h is split hi/lo into two LDS arrays.
// GEMM per fragment: 3 MFMA terms  hi*Whi + lo*Whi + hi*Wlo  (lo*lo dropped,
// ~1e-6) -> emulated-f32 accuracy.  The step map iz^2-iz is locally expansive
// (|2iz-1| up to ~2), so single-bf16 error (2e-3/step) amplifies ~100x to the
// 0.16 measured in round 7; split-bf16 injects ~2e-6/step like f32 reassoc.
__global__ __launch_bounds__(512, 2) void scan_kernel(
    const float* __restrict__ Wr, const float* __restrict__ h0,
    float* __restrict__ out, unsigned* __restrict__ bar)
{
    __shared__ __align__(16) char hs_hi[16 * 2048];   // bf16 h_hi[16][1024], XOR-swizzled
    __shared__ __align__(16) char hs_lo[16 * 2048];   // bf16 h_lo residuals
    // pl partials OVERLAY hs_hi (8.7 KB) — only live between the post-MFMA
    // barrier and the reduce barrier; hs is dead there, restaged next step.
    float* pl = reinterpret_cast<float*>(hs_hi);      // [4][2][16][17]

    const int tid  = threadIdx.x;
    const int lane = tid & 63;
    const int w    = tid >> 6;          // wave 0..7
    const int bid  = (int)blockIdx.x;
    const int g    = bid >> 4;          // group 0..15
    const int mem  = bid & 15;          // member 0..15
    const int b0   = g * 16;
    const int col0 = mem * 64;

    const int ct = w >> 1;              // col tile 0..3 (16 cols)
    const int kh = w & 1;               // K half 0..1 (K=512)
    const int tcol0 = col0 + ct * 16;

    // ---- prologue: B-fragments (Wr bf16 hi+lo, diag zeroed) into registers ----
    // Fragment f covers K in [kh*512+32f, +32). Lane l holds B[k][col]:
    // col = tcol0 + (l&15), k = kh*512 + 32f + (l>>4)*8 + e, e=0..7.
    short8v bhi[16], blo[16];
    {
        const int bcol  = tcol0 + (lane & 15);
        const int krow0 = kh * 512 + (lane >> 4) * 8;
        #pragma unroll
        for (int f = 0; f < 16; ++f) {
            short8v rh, rl;
            #pragma unroll
            for (int e = 0; e < 8; ++e) {
                const int k = krow0 + f * 32 + e;
                float v = Wr[(size_t)k * Uu + bcol];
                if (k == bcol) v = 0.f;           // tf.set_diag(..., 0)
                const uint16_t hb = f2bf_bits(v);
                rh[e] = (short)hb;
                rl[e] = (short)f2bf_bits(v - bfbits2f(hb));
            }
            bhi[f] = rh;  blo[f] = rl;
        }
    }

    // A-frag read: lane l reads row=l&15, logical byte kh*1024 + 64f + (l>>4)*16,
    // physical = row*2048 + (logical ^ ((row&7)<<4))  — XOR on FULL offset.
    const int  arow   = lane & 15;
    const int  asw    = (arow & 7) << 4;
    const int  abase  = kh * 1024 + ((lane >> 4) * 16);

    // staging mapping: thread -> (row srow, 64B chunk scb of the 2048B bf16 row)
    const int srow = tid >> 5;          // 0..15
    const int scb  = (tid & 31) * 64;
    const int ssw  = (srow & 7) << 4;

    // reduce mapping: thread -> (sample rs, col pair rc)
    const int rs  = tid >> 5;           // 0..15
    const int rc  = (tid & 31) * 2;     // 0..62
    const int rct = rc >> 4;
    const int rcc = rc & 15;

    unsigned* cnt = bar + g * 64;       // 256B-spaced counters

    for (int t = 0; t < Tt; ++t) {
        // xi prefetch (this thread's 2 outputs; nobody else touches them)
        float* orow = &out[((size_t)(b0 + rs) * Tt + t) * Uu + col0 + rc];
        float2 xiv = __builtin_bit_cast(float2,
            __builtin_nontemporal_load(reinterpret_cast<const uint64_t*>(orow)));

        // ---- stage h[16][1024] f32 -> split bf16 hi/lo in swizzled LDS ----
        {
            const float* src = (t == 0)
                ? (h0 + (size_t)(b0 + srow) * Uu)
                : (out + ((size_t)(b0 + srow) * Tt + (t - 1)) * Uu);
            const int e0 = scb >> 1;    // 32 elements per thread
            #pragma unroll
            for (int j = 0; j < 4; ++j) {
                uint64_t a = llc_load_u64(src + e0 + j * 8);
                uint64_t b = llc_load_u64(src + e0 + j * 8 + 2);
                uint64_t c = llc_load_u64(src + e0 + j * 8 + 4);
                uint64_t d = llc_load_u64(src + e0 + j * 8 + 6);
                float2 fa = __builtin_bit_cast(float2, a);
                float2 fb = __builtin_bit_cast(float2, b);
                float2 fc = __builtin_bit_cast(float2, c);
                float2 fd = __builtin_bit_cast(float2, d);
                uint4 qh, ql;
                split2(fa.x, fa.y, qh.x, ql.x);
                split2(fb.x, fb.y, qh.y, ql.y);
                split2(fc.x, fc.y, qh.z, ql.z);
                split2(fd.x, fd.y, qh.w, ql.w);
                const int off = srow * 2048 + ((scb + j * 16) ^ ssw);
                *reinterpret_cast<uint4*>(hs_hi + off) = qh;
                *reinterpret_cast<uint4*>(hs_lo + off) = ql;
            }
        }
        __syncthreads();

        // ---- MFMA: 16 frags x 3 terms (hi*Whi, lo*Whi, hi*Wlo) ----
        f32x4 a0 = {0.f, 0.f, 0.f, 0.f};
        f32x4 a1 = {0.f, 0.f, 0.f, 0.f};
        f32x4 a2 = {0.f, 0.f, 0.f, 0.f};
        #pragma unroll
        for (int f = 0; f < 16; ++f) {
            const int off = arow * 2048 + ((abase + 64 * f) ^ asw);
            short8v ahi = *reinterpret_cast<const short8v*>(hs_hi + off);
            short8v alo = *reinterpret_cast<const short8v*>(hs_lo + off);
            a0 = __builtin_amdgcn_mfma_f32_16x16x32_bf16(ahi, bhi[f], a0, 0, 0, 0);
            a1 = __builtin_amdgcn_mfma_f32_16x16x32_bf16(alo, bhi[f], a1, 0, 0, 0);
            a2 = __builtin_amdgcn_mfma_f32_16x16x32_bf16(ahi, blo[f], a2, 0, 0, 0);
        }
        const f32x4 accv = (a0 + a1) + a2;

        __syncthreads();   // all waves done READING hs before pl overlays it

        // ---- partials: C/D layout col=lane&15, row=(lane>>4)*4+j ----
        {
            const int prow0 = (lane >> 4) * 4;
            #pragma unroll
            for (int j = 0; j < 4; ++j)
                pl[(((ct * 2 + kh) * 16) + prow0 + j) * 17 + (lane & 15)] = accv[j];
        }
        __syncthreads();

        // ---- reduce 2 K-halves + xi + pointwise + store ----
        {
            const int base0 = ((rct * 2 + 0) * 16 + rs) * 17 + rcc;
            const int base1 = ((rct * 2 + 1) * 16 + rs) * 17 + rcc;
            float v0 = pl[base0]     + pl[base1];
            float v1 = pl[base0 + 1] + pl[base1 + 1];
            float iz0 = xiv.x + v0;
            float iz1 = xiv.y + v1;
            float o0 = iz0 * iz0 - iz0;
            float o1 = iz1 * iz1 - iz1;
            o0 = fminf(fmaxf(o0, -1.f), 1.f);
            o1 = fminf(fmaxf(o1, -1.f), 1.f);
            llc_store_f2(orow, make_float2(o0, o1));
        }

        // ---- 16-way group barrier: relaxed counter, no fences ----
        __syncthreads();        // drains vmcnt(0): all LLC stores at coherence point
        if (tid == 0) {
            __hip_atomic_fetch_add(cnt, 1u, __ATOMIC_RELAXED, __HIP_MEMORY_SCOPE_AGENT);
            const unsigned target = 16u * (unsigned)(t + 1);
            while (__hip_atomic_load(cnt, __ATOMIC_RELAXED, __HIP_MEMORY_SCOPE_AGENT) < target)
                __builtin_amdgcn_s_sleep(2);
        }
        __syncthreads();
    }
}

extern "C" void kernel_launch(void* const* d_in, const int* in_sizes, int n_in,
                              void* d_out, int out_size, void* d_ws, size_t ws_size,
                              hipStream_t stream) {
    const float* x  = (const float*)d_in[0];
    const float* h0 = (const float*)d_in[1];
    const float* Wi = (const float*)d_in[2];
    const float* b  = (const float*)d_in[3];
    const float* Wr = (const float*)d_in[4];
    float* out = (float*)d_out;

    unsigned* bar = (unsigned*)d_ws;     // 8 KB of counters

    init_bar_kernel<<<1, 64, 0, stream>>>(bar);

    dim3 g1((Bb * Tt) / 64, Uu / 64);
    xi_gemm_kernel<<<g1, 256, 0, stream>>>(x, Wi, b, out);

    void* args[] = { (void*)&Wr, (void*)&h0, (void*)&out, (void*)&bar };
    hipLaunchCooperativeKernel((const void*)scan_kernel, dim3(256), dim3(512),
                               args, 0, stream);
}

// Round 10
// 1762.673 us; speedup vs baseline: 6.0706x; 1.0077x over previous
//
#include <hip/hip_runtime.h>
#include <hip/hip_bf16.h>
#include <cstdint>

#define Bb 256
#define Tt 128
#define Dd 512
#define Uu 1024

typedef __attribute__((ext_vector_type(8))) short short8v;  // 8 bf16 = 4 VGPRs
typedef __attribute__((ext_vector_type(4))) float f32x4;

// ---------------- Kernel 1: xi = x @ W_i + b -> d_out[b][t][u] (f32 VALU, unchanged) ----
__global__ __launch_bounds__(256, 1) void xi_gemm_kernel(
    const float* __restrict__ x, const float* __restrict__ Wi,
    const float* __restrict__ bias, float* __restrict__ out)
{
    __shared__ __align__(16) float As[16][64];   // [k][m]
    __shared__ __align__(16) float Bs[16][64];   // [k][n]
    const int tid  = threadIdx.x;
    const int row0 = blockIdx.x * 64;
    const int col0 = blockIdx.y * 64;
    const int tr = tid >> 4;
    const int tc = tid & 15;
    const int ra  = tid & 63;
    const int k4a = tid >> 6;
    const int kb  = tid >> 4;
    const int c4b = tid & 15;

    float acc[4][4] = {};

    for (int k0 = 0; k0 < Dd; k0 += 16) {
        float4 av = *reinterpret_cast<const float4*>(&x[(size_t)(row0 + ra) * Dd + k0 + k4a * 4]);
        float4 bv = *reinterpret_cast<const float4*>(&Wi[(size_t)(k0 + kb) * Uu + col0 + c4b * 4]);
        __syncthreads();
        As[k4a*4+0][ra] = av.x;
        As[k4a*4+1][ra] = av.y;
        As[k4a*4+2][ra] = av.z;
        As[k4a*4+3][ra] = av.w;
        *reinterpret_cast<float4*>(&Bs[kb][c4b*4]) = bv;
        __syncthreads();
        #pragma unroll
        for (int kk = 0; kk < 16; ++kk) {
            float4 a = *reinterpret_cast<const float4*>(&As[kk][tr*4]);
            float4 b = *reinterpret_cast<const float4*>(&Bs[kk][tc*4]);
            float aa[4] = {a.x, a.y, a.z, a.w};
            float bb[4] = {b.x, b.y, b.z, b.w};
            #pragma unroll
            for (int i = 0; i < 4; ++i)
                #pragma unroll
                for (int j = 0; j < 4; ++j)
                    acc[i][j] += aa[i] * bb[j];
        }
    }

    float4 bv = *reinterpret_cast<const float4*>(&bias[col0 + tc*4]);
    #pragma unroll
    for (int i = 0; i < 4; ++i) {
        float4 o;
        o.x = acc[i][0] + bv.x;  o.y = acc[i][1] + bv.y;
        o.z = acc[i][2] + bv.z;  o.w = acc[i][3] + bv.w;
        *reinterpret_cast<float4*>(&out[(size_t)(row0 + tr*4 + i) * Uu + col0 + tc*4]) = o;
    }
}

// ---------------- init: zero barrier storage (covers flags AND counters) ----
__global__ void init_bar_kernel(unsigned* __restrict__ bar) {
    bar[threadIdx.x] = 0u;    // 1024 uints = 4 KB
}

// LLC-coherent (fence-free device-scope) primitives: relaxed agent atomics ->
// global ops with sc0 sc1 (bypass L1/L2, no buffer_inv) — cross-XCD correct,
// leave per-XCD L2 untouched.
__device__ __forceinline__ uint64_t llc_load_u64(const void* p) {
    return __hip_atomic_load((const uint64_t*)p, __ATOMIC_RELAXED,
                             __HIP_MEMORY_SCOPE_AGENT);
}
__device__ __forceinline__ uint32_t llc_load_u32(const void* p) {
    return __hip_atomic_load((const uint32_t*)p, __ATOMIC_RELAXED,
                             __HIP_MEMORY_SCOPE_AGENT);
}
__device__ __forceinline__ void llc_store_u32(void* p, uint32_t v) {
    __hip_atomic_store((uint32_t*)p, v, __ATOMIC_RELAXED,
                       __HIP_MEMORY_SCOPE_AGENT);
}
__device__ __forceinline__ void llc_store_f2(float* p, float2 v) {
    __hip_atomic_store((uint64_t*)p, __builtin_bit_cast(uint64_t, v),
                       __ATOMIC_RELAXED, __HIP_MEMORY_SCOPE_AGENT);
}

__device__ __forceinline__ uint16_t f2bf_bits(float x) {
    union { __hip_bfloat16 h; uint16_t u; } c;
    c.h = __float2bfloat16(x);
    return c.u;
}
__device__ __forceinline__ float bfbits2f(uint16_t b) {
    uint32_t u = ((uint32_t)b) << 16;
    return __builtin_bit_cast(float, u);
}
__device__ __forceinline__ void split2(float x, float y, uint32_t& hi, uint32_t& lo) {
    const uint16_t hx = f2bf_bits(x), hy = f2bf_bits(y);
    const uint16_t lx = f2bf_bits(x - bfbits2f(hx));
    const uint16_t ly = f2bf_bits(y - bfbits2f(hy));
    hi = (uint32_t)hx | ((uint32_t)hy << 16);
    lo = (uint32_t)lx | ((uint32_t)ly << 16);
}

// ============ Kernel 2a: 512 wgs (2/CU), 16 groups x 32 members ============
// LDS exactly 64 KB (hs_hi 32K + hs_lo 32K, pl OVERLAYS hs_hi) -> 2 wg/CU fits
// 128 KB <= 160 KB.  Wave w of 8: col-tile ct=w>>2 (16 cols of the member's
// 32), K-quarter kq=w&3 (256).  Wr register-resident bf16 hi+lo (64 VGPR),
// diag zeroed; 3-term MFMA = emulated f32 (r8-verified).  Flag barrier:
// member stores flag[g*32+mem]=t+1 (no RMW chain), wave-0 lanes 0..31 poll.
__global__ __launch_bounds__(512, 4) void scan_kernel2(
    const float* __restrict__ Wr, const float* __restrict__ h0,
    float* __restrict__ out, unsigned* __restrict__ flags)
{
    __shared__ __align__(16) char hs_hi[16 * 2048];   // bf16 h_hi[16][1024], XOR-swizzled
    __shared__ __align__(16) char hs_lo[16 * 2048];   // bf16 h_lo residuals
    float* pl = reinterpret_cast<float*>(hs_hi);      // [2][4][16][17] overlay, 8.7 KB

    const int tid  = threadIdx.x;
    const int lane = tid & 63;
    const int w    = tid >> 6;          // wave 0..7
    const int bid  = (int)blockIdx.x;
    const int g    = bid >> 5;          // group 0..15
    const int mem  = bid & 31;          // member 0..31
    const int b0   = g * 16;
    const int col0 = mem * 32;

    const int ct = w >> 2;              // col tile 0..1 (16 cols)
    const int kq = w & 3;               // K quarter 0..3 (K=256)
    const int tcol0 = col0 + ct * 16;

    // ---- prologue: B-fragments (Wr bf16 hi+lo, diag zeroed) ----
    short8v bhi[8], blo[8];
    {
        const int bcol  = tcol0 + (lane & 15);
        const int krow0 = kq * 256 + (lane >> 4) * 8;
        #pragma unroll
        for (int f = 0; f < 8; ++f) {
            short8v rh, rl;
            #pragma unroll
            for (int e = 0; e < 8; ++e) {
                const int k = krow0 + f * 32 + e;
                float v = Wr[(size_t)k * Uu + bcol];
                if (k == bcol) v = 0.f;           // tf.set_diag(..., 0)
                const uint16_t hb = f2bf_bits(v);
                rh[e] = (short)hb;
                rl[e] = (short)f2bf_bits(v - bfbits2f(hb));
            }
            bhi[f] = rh;  blo[f] = rl;
        }
    }

    // A-frag read: row=lane&15, logical byte kq*512 + 64f + (lane>>4)*16,
    // physical = row*2048 + (logical ^ ((row&7)<<4))  — XOR on FULL offset.
    const int  arow   = lane & 15;
    const int  asw    = (arow & 7) << 4;
    const int  abase  = kq * 512 + ((lane >> 4) * 16);

    // staging: half-wave per row, lane-contiguous 16B chunks (conflict-free)
    const int srow = tid >> 5;          // 0..15
    const int l5   = tid & 31;
    const int ssw  = (srow & 7) << 4;

    // reduce: thread -> one element (sample rs, col rcol)
    const int rs   = tid >> 5;          // 0..15
    const int rcol = tid & 31;          // 0..31
    const int rct  = rcol >> 4;
    const int rcc  = rcol & 15;

    unsigned* flagp = flags + g * 32;

    for (int t = 0; t < Tt; ++t) {
        float* oelem = &out[((size_t)(b0 + rs) * Tt + t) * Uu + col0 + rcol];
        const uint32_t xibits = __builtin_nontemporal_load(
            reinterpret_cast<const uint32_t*>(oelem));

        // ---- stage h[16][1024] f32 -> split bf16 hi/lo, swizzled ----
        {
            const float* src = (t == 0)
                ? (h0 + (size_t)(b0 + srow) * Uu)
                : (out + ((size_t)(b0 + srow) * Tt + (t - 1)) * Uu);
            #pragma unroll
            for (int j = 0; j < 4; ++j) {
                const int kb = l5 * 16 + j * 512;    // byte in 2048B bf16 row
                const int e0 = kb >> 1;              // 8 f32 elements
                uint64_t a = llc_load_u64(src + e0);
                uint64_t b = llc_load_u64(src + e0 + 2);
                uint64_t c = llc_load_u64(src + e0 + 4);
                uint64_t d = llc_load_u64(src + e0 + 6);
                float2 fa = __builtin_bit_cast(float2, a);
                float2 fb = __builtin_bit_cast(float2, b);
                float2 fc = __builtin_bit_cast(float2, c);
                float2 fd = __builtin_bit_cast(float2, d);
                uint4 qh, ql;
                split2(fa.x, fa.y, qh.x, ql.x);
                split2(fb.x, fb.y, qh.y, ql.y);
                split2(fc.x, fc.y, qh.z, ql.z);
                split2(fd.x, fd.y, qh.w, ql.w);
                const int off = srow * 2048 + (kb ^ ssw);
                *reinterpret_cast<uint4*>(hs_hi + off) = qh;
                *reinterpret_cast<uint4*>(hs_lo + off) = ql;
            }
        }
        __syncthreads();

        // ---- MFMA: 8 frags x 3 terms ----
        f32x4 a0 = {0.f, 0.f, 0.f, 0.f};
        f32x4 a1 = {0.f, 0.f, 0.f, 0.f};
        f32x4 a2 = {0.f, 0.f, 0.f, 0.f};
        #pragma unroll
        for (int f = 0; f < 8; ++f) {
            const int off = arow * 2048 + ((abase + 64 * f) ^ asw);
            short8v ahi = *reinterpret_cast<const short8v*>(hs_hi + off);
            short8v alo = *reinterpret_cast<const short8v*>(hs_lo + off);
            a0 = __builtin_amdgcn_mfma_f32_16x16x32_bf16(ahi, bhi[f], a0, 0, 0, 0);
            a1 = __builtin_amdgcn_mfma_f32_16x16x32_bf16(alo, bhi[f], a1, 0, 0, 0);
            a2 = __builtin_amdgcn_mfma_f32_16x16x32_bf16(ahi, blo[f], a2, 0, 0, 0);
        }
        const f32x4 accv = (a0 + a1) + a2;

        __syncthreads();   // all waves done READING hs_hi before pl overlays it

        // ---- partials: C/D layout col=lane&15, row=(lane>>4)*4+j ----
        {
            const int prow0 = (lane >> 4) * 4;
            #pragma unroll
            for (int j = 0; j < 4; ++j)
                pl[(((ct * 4 + kq) * 16) + prow0 + j) * 17 + (lane & 15)] = accv[j];
        }
        __syncthreads();

        // ---- reduce 4 K-quarters + xi + pointwise + store ----
        {
            const int base = (rct * 4 * 16 + rs) * 17 + rcc;
            float v = pl[base] + pl[base + 16 * 17] + pl[base + 32 * 17] + pl[base + 48 * 17];
            float iz = __builtin_bit_cast(float, xibits) + v;
            float o  = iz * iz - iz;
            o = fminf(fmaxf(o, -1.f), 1.f);
            llc_store_u32(oelem, __builtin_bit_cast(uint32_t, o));
        }

        // ---- group barrier: flag stores + wave-0 ballot poll (no RMW) ----
        __syncthreads();        // drains vmcnt(0): all LLC stores at coherence point
        if (tid == 0) llc_store_u32(flagp + mem, (unsigned)(t + 1));
        if (w == 0) {
            const unsigned tgt = (unsigned)(t + 1);
            for (;;) {
                unsigned v = (lane < 32) ? llc_load_u32(flagp + lane) : tgt;
                if (__all((int)(v >= tgt))) break;
                __builtin_amdgcn_s_sleep(1);
            }
        }
        __syncthreads();
    }
}

// ============ Kernel 2b: FALLBACK — r8 kernel verbatim (proven pass) ============
// 256 wgs = 16 groups x 16 members, counter barrier, 64 KB LDS.
__global__ __launch_bounds__(512, 2) void scan_kernel1(
    const float* __restrict__ Wr, const float* __restrict__ h0,
    float* __restrict__ out, unsigned* __restrict__ bar)
{
    __shared__ __align__(16) char hs_hi[16 * 2048];
    __shared__ __align__(16) char hs_lo[16 * 2048];
    float* pl = reinterpret_cast<float*>(hs_hi);      // [4][2][16][17]

    const int tid  = threadIdx.x;
    const int lane = tid & 63;
    const int w    = tid >> 6;
    const int bid  = (int)blockIdx.x;
    const int g    = bid >> 4;
    const int mem  = bid & 15;
    const int b0   = g * 16;
    const int col0 = mem * 64;

    const int ct = w >> 1;
    const int kh = w & 1;
    const int tcol0 = col0 + ct * 16;

    short8v bhi[16], blo[16];
    {
        const int bcol  = tcol0 + (lane & 15);
        const int krow0 = kh * 512 + (lane >> 4) * 8;
        #pragma unroll
        for (int f = 0; f < 16; ++f) {
            short8v rh, rl;
            #pragma unroll
            for (int e = 0; e < 8; ++e) {
                const int k = krow0 + f * 32 + e;
                float v = Wr[(size_t)k * Uu + bcol];
                if (k == bcol) v = 0.f;
                const uint16_t hb = f2bf_bits(v);
                rh[e] = (short)hb;
                rl[e] = (short)f2bf_bits(v - bfbits2f(hb));
            }
            bhi[f] = rh;  blo[f] = rl;
        }
    }

    const int  arow   = lane & 15;
    const int  asw    = (arow & 7) << 4;
    const int  abase  = kh * 1024 + ((lane >> 4) * 16);

    const int srow = tid >> 5;
    const int scb  = (tid & 31) * 64;
    const int ssw  = (srow & 7) << 4;

    const int rs  = tid >> 5;
    const int rc  = (tid & 31) * 2;
    const int rct = rc >> 4;
    const int rcc = rc & 15;

    unsigned* cnt = bar + g * 64;

    for (int t = 0; t < Tt; ++t) {
        float* orow = &out[((size_t)(b0 + rs) * Tt + t) * Uu + col0 + rc];
        float2 xiv = __builtin_bit_cast(float2,
            __builtin_nontemporal_load(reinterpret_cast<const uint64_t*>(orow)));

        {
            const float* src = (t == 0)
                ? (h0 + (size_t)(b0 + srow) * Uu)
                : (out + ((size_t)(b0 + srow) * Tt + (t - 1)) * Uu);
            const int e0 = scb >> 1;
            #pragma unroll
            for (int j = 0; j < 4; ++j) {
                uint64_t a = llc_load_u64(src + e0 + j * 8);
                uint64_t b = llc_load_u64(src + e0 + j * 8 + 2);
                uint64_t c = llc_load_u64(src + e0 + j * 8 + 4);
                uint64_t d = llc_load_u64(src + e0 + j * 8 + 6);
                float2 fa = __builtin_bit_cast(float2, a);
                float2 fb = __builtin_bit_cast(float2, b);
                float2 fc = __builtin_bit_cast(float2, c);
                float2 fd = __builtin_bit_cast(float2, d);
                uint4 qh, ql;
                split2(fa.x, fa.y, qh.x, ql.x);
                split2(fb.x, fb.y, qh.y, ql.y);
                split2(fc.x, fc.y, qh.z, ql.z);
                split2(fd.x, fd.y, qh.w, ql.w);
                const int off = srow * 2048 + ((scb + j * 16) ^ ssw);
                *reinterpret_cast<uint4*>(hs_hi + off) = qh;
                *reinterpret_cast<uint4*>(hs_lo + off) = ql;
            }
        }
        __syncthreads();

        f32x4 a0 = {0.f, 0.f, 0.f, 0.f};
        f32x4 a1 = {0.f, 0.f, 0.f, 0.f};
        f32x4 a2 = {0.f, 0.f, 0.f, 0.f};
        #pragma unroll
        for (int f = 0; f < 16; ++f) {
            const int off = arow * 2048 + ((abase + 64 * f) ^ asw);
            short8v ahi = *reinterpret_cast<const short8v*>(hs_hi + off);
            short8v alo = *reinterpret_cast<const short8v*>(hs_lo + off);
            a0 = __builtin_amdgcn_mfma_f32_16x16x32_bf16(ahi, bhi[f], a0, 0, 0, 0);
            a1 = __builtin_amdgcn_mfma_f32_16x16x32_bf16(alo, bhi[f], a1, 0, 0, 0);
            a2 = __builtin_amdgcn_mfma_f32_16x16x32_bf16(ahi, blo[f], a2, 0, 0, 0);
        }
        const f32x4 accv = (a0 + a1) + a2;

        __syncthreads();

        {
            const int prow0 = (lane >> 4) * 4;
            #pragma unroll
            for (int j = 0; j < 4; ++j)
                pl[(((ct * 2 + kh) * 16) + prow0 + j) * 17 + (lane & 15)] = accv[j];
        }
        __syncthreads();

        {
            const int base0 = ((rct * 2 + 0) * 16 + rs) * 17 + rcc;
            const int base1 = ((rct * 2 + 1) * 16 + rs) * 17 + rcc;
            float v0 = pl[base0]     + pl[base1];
            float v1 = pl[base0 + 1] + pl[base1 + 1];
            float iz0 = xiv.x + v0;
            float iz1 = xiv.y + v1;
            float o0 = iz0 * iz0 - iz0;
            float o1 = iz1 * iz1 - iz1;
            o0 = fminf(fmaxf(o0, -1.f), 1.f);
            o1 = fminf(fmaxf(o1, -1.f), 1.f);
            llc_store_f2(orow, make_float2(o0, o1));
        }

        __syncthreads();
        if (tid == 0) {
            __hip_atomic_fetch_add(cnt, 1u, __ATOMIC_RELAXED, __HIP_MEMORY_SCOPE_AGENT);
            const unsigned target = 16u * (unsigned)(t + 1);
            while (__hip_atomic_load(cnt, __ATOMIC_RELAXED, __HIP_MEMORY_SCOPE_AGENT) < target)
                __builtin_amdgcn_s_sleep(2);
        }
        __syncthreads();
    }
}

extern "C" void kernel_launch(void* const* d_in, const int* in_sizes, int n_in,
                              void* d_out, int out_size, void* d_ws, size_t ws_size,
                              hipStream_t stream) {
    const float* x  = (const float*)d_in[0];
    const float* h0 = (const float*)d_in[1];
    const float* Wi = (const float*)d_in[2];
    const float* b  = (const float*)d_in[3];
    const float* Wr = (const float*)d_in[4];
    float* out = (float*)d_out;

    unsigned* bar = (unsigned*)d_ws;   // 4 KB: flags (512) / counters (stride 64)

    init_bar_kernel<<<1, 1024, 0, stream>>>(bar);

    dim3 g1((Bb * Tt) / 64, Uu / 64);
    xi_gemm_kernel<<<g1, 256, 0, stream>>>(x, Wi, b, out);

    // Host-side occupancy gate (deterministic, graph-capture-safe: no stream ops)
    int nb = 0;
    hipError_t oe = hipOccupancyMaxActiveBlocksPerMultiprocessor(
        &nb, reinterpret_cast<const void*>(scan_kernel2), 512, 0);

    void* args[] = { (void*)&Wr, (void*)&h0, (void*)&out, (void*)&bar };
    if (oe == hipSuccess && nb >= 2) {
        hipLaunchCooperativeKernel((const void*)scan_kernel2, dim3(512), dim3(512),
                                   args, 0, stream);
    } else {
        hipLaunchCooperativeKernel((const void*)scan_kernel1, dim3(256), dim3(512),
                                   args, 0, stream);
    }
}

// Round 15
// 1483.212 us; speedup vs baseline: 7.2143x; 1.1884x over previous
//
#include <hip/hip_runtime.h>
#include <hip/hip_bf16.h>
#include <cstdint>

#define Bb 256
#define Tt 128
#define Dd 512
#define Uu 1024

typedef __attribute__((ext_vector_type(8))) short short8v;  // 8 bf16 = 4 VGPRs
typedef __attribute__((ext_vector_type(4))) float f32x4;

// ---------------- init: zero barrier storage ----------------
__global__ void init_bar_kernel(unsigned* __restrict__ bar) {
    bar[threadIdx.x] = 0u;    // 1024 uints = 4 KB (covers counters at g*64)
}

// ---------------- LLC-coherent (fence-free device-scope) primitives ----------------
__device__ __forceinline__ uint64_t llc_load_u64(const void* p) {
    return __hip_atomic_load((const uint64_t*)p, __ATOMIC_RELAXED,
                             __HIP_MEMORY_SCOPE_AGENT);
}
__device__ __forceinline__ void llc_store_f2(float* p, float2 v) {
    __hip_atomic_store((uint64_t*)p, __builtin_bit_cast(uint64_t, v),
                       __ATOMIC_RELAXED, __HIP_MEMORY_SCOPE_AGENT);
}

__device__ __forceinline__ uint16_t f2bf_bits(float x) {
    union { __hip_bfloat16 h; uint16_t u; } c;
    c.h = __float2bfloat16(x);
    return c.u;
}
__device__ __forceinline__ float bfbits2f(uint16_t b) {
    uint32_t u = ((uint32_t)b) << 16;
    return __builtin_bit_cast(float, u);
}
__device__ __forceinline__ void split2(float x, float y, uint32_t& hi, uint32_t& lo) {
    const uint16_t hx = f2bf_bits(x), hy = f2bf_bits(y);
    const uint16_t lx = f2bf_bits(x - bfbits2f(hx));
    const uint16_t ly = f2bf_bits(y - bfbits2f(hy));
    hi = (uint32_t)hx | ((uint32_t)hy << 16);
    lo = (uint32_t)lx | ((uint32_t)ly << 16);
}

// ---------------- Wi transpose+split: WiT_hi/lo[c][k] bf16, k-contiguous ----------
// tile stride 36 floats = 144 B (multiple of 16) -> aligned float4 LDS stores.
__global__ __launch_bounds__(256, 4) void wi_split_kernel(
    const float* __restrict__ Wi, uint16_t* __restrict__ WiT_hi,
    uint16_t* __restrict__ WiT_lo)
{
    __shared__ float tile[32][36];
    const int k0 = blockIdx.x * 32;
    const int c0 = blockIdx.y * 32;
    {
        const int r  = threadIdx.x >> 3;
        const int c4 = (threadIdx.x & 7) * 4;
        *reinterpret_cast<float4*>(&tile[r][c4]) =
            *reinterpret_cast<const float4*>(&Wi[(size_t)(k0 + r) * Uu + c0 + c4]);
    }
    __syncthreads();
    {
        const int c  = threadIdx.x >> 3;
        const int k4 = (threadIdx.x & 7) * 4;
        uint16_t h[4], l[4];
        #pragma unroll
        for (int i = 0; i < 4; ++i) {
            float v = tile[k4 + i][c];
            h[i] = f2bf_bits(v);
            l[i] = f2bf_bits(v - bfbits2f(h[i]));
        }
        uint64_t hp = (uint64_t)h[0] | ((uint64_t)h[1] << 16)
                    | ((uint64_t)h[2] << 32) | ((uint64_t)h[3] << 48);
        uint64_t lp = (uint64_t)l[0] | ((uint64_t)l[1] << 16)
                    | ((uint64_t)l[2] << 32) | ((uint64_t)l[3] << 48);
        const size_t off = (size_t)(c0 + c) * Dd + k0 + k4;
        *reinterpret_cast<uint64_t*>(&WiT_hi[off]) = hp;
        *reinterpret_cast<uint64_t*>(&WiT_lo[off]) = lp;
    }
}

// ---------------- xi = x @ Wi + b via split-bf16 MFMA ----------------
// 512 thr (8 waves), BM=64, BN=256, BK=64; wave = 32-col n-quarter.
// Fragment conventions identical to the r8-verified scan kernel.
__global__ __launch_bounds__(512, 4) void xi_mfma_kernel(
    const float* __restrict__ x, const uint16_t* __restrict__ WiT_hi,
    const uint16_t* __restrict__ WiT_lo, const float* __restrict__ bias,
    float* __restrict__ out)
{
    __shared__ __align__(16) char xs_hi[64 * 128];
    __shared__ __align__(16) char xs_lo[64 * 128];

    const int tid  = threadIdx.x;
    const int lane = tid & 63;
    const int nq   = tid >> 6;
    const int rowb = blockIdx.x * 64;
    const int colw = blockIdx.y * 256 + nq * 32;

    const int sr  = tid >> 3;
    const int k8  = (tid & 7) * 8;
    const int ssw = (sr & 7) << 4;

    const int arow_l = lane & 15;
    const int akl    = (lane >> 4) * 16;
    const int kl     = (lane >> 4) * 8;

    const uint16_t* wh[2];
    const uint16_t* wl[2];
    float bv[2];
    #pragma unroll
    for (int nt = 0; nt < 2; ++nt) {
        const int c = colw + nt * 16 + arow_l;
        wh[nt] = WiT_hi + (size_t)c * Dd;
        wl[nt] = WiT_lo + (size_t)c * Dd;
        bv[nt] = bias[c];
    }

    f32x4 acc[4][2];
    #pragma unroll
    for (int mt = 0; mt < 4; ++mt)
        #pragma unroll
        for (int nt = 0; nt < 2; ++nt)
            acc[mt][nt] = (f32x4){0.f, 0.f, 0.f, 0.f};

    for (int k0 = 0; k0 < Dd; k0 += 64) {
        {
            const float* src = &x[(size_t)(rowb + sr) * Dd + k0 + k8];
            float4 a = *reinterpret_cast<const float4*>(src);
            float4 b = *reinterpret_cast<const float4*>(src + 4);
            uint4 qh, ql;
            split2(a.x, a.y, qh.x, ql.x);
            split2(a.z, a.w, qh.y, ql.y);
            split2(b.x, b.y, qh.z, ql.z);
            split2(b.z, b.w, qh.w, ql.w);
            const int off = sr * 128 + ((k8 * 2) ^ ssw);
            *reinterpret_cast<uint4*>(xs_hi + off) = qh;
            *reinterpret_cast<uint4*>(xs_lo + off) = ql;
        }
        __syncthreads();

        #pragma unroll
        for (int fl = 0; fl < 2; ++fl) {
            short8v bh[2], bl[2];
            #pragma unroll
            for (int nt = 0; nt < 2; ++nt) {
                const int kb = k0 + fl * 32 + kl;
                bh[nt] = *reinterpret_cast<const short8v*>(wh[nt] + kb);
                bl[nt] = *reinterpret_cast<const short8v*>(wl[nt] + kb);
            }
            #pragma unroll
            for (int mt = 0; mt < 4; ++mt) {
                const int row = mt * 16 + arow_l;
                const int off = row * 128 + ((fl * 64 + akl) ^ ((row & 7) << 4));
                short8v ah = *reinterpret_cast<const short8v*>(xs_hi + off);
                short8v al = *reinterpret_cast<const short8v*>(xs_lo + off);
                #pragma unroll
                for (int nt = 0; nt < 2; ++nt) {
                    acc[mt][nt] = __builtin_amdgcn_mfma_f32_16x16x32_bf16(ah, bh[nt], acc[mt][nt], 0, 0, 0);
                    acc[mt][nt] = __builtin_amdgcn_mfma_f32_16x16x32_bf16(al, bh[nt], acc[mt][nt], 0, 0, 0);
                    acc[mt][nt] = __builtin_amdgcn_mfma_f32_16x16x32_bf16(ah, bl[nt], acc[mt][nt], 0, 0, 0);
                }
            }
        }
        __syncthreads();
    }

    const int prow = (lane >> 4) * 4;
    #pragma unroll
    for (int mt = 0; mt < 4; ++mt)
        #pragma unroll
        for (int nt = 0; nt < 2; ++nt)
            #pragma unroll
            for (int j = 0; j < 4; ++j)
                out[(size_t)(rowb + mt * 16 + prow + j) * Uu + colw + nt * 16 + arow_l]
                    = acc[mt][nt][j] + bv[nt];
}

// ---------------- FALLBACK xi (f32 VALU, proven) ----------------
__global__ __launch_bounds__(256, 1) void xi_gemm_kernel(
    const float* __restrict__ x, const float* __restrict__ Wi,
    const float* __restrict__ bias, float* __restrict__ out)
{
    __shared__ __align__(16) float As[16][64];
    __shared__ __align__(16) float Bs[16][64];
    const int tid  = threadIdx.x;
    const int row0 = blockIdx.x * 64;
    const int col0 = blockIdx.y * 64;
    const int tr = tid >> 4, tc = tid & 15;
    const int ra = tid & 63, k4a = tid >> 6, kb = tid >> 4, c4b = tid & 15;
    float acc[4][4] = {};
    for (int k0 = 0; k0 < Dd; k0 += 16) {
        float4 av = *reinterpret_cast<const float4*>(&x[(size_t)(row0 + ra) * Dd + k0 + k4a * 4]);
        float4 bv = *reinterpret_cast<const float4*>(&Wi[(size_t)(k0 + kb) * Uu + col0 + c4b * 4]);
        __syncthreads();
        As[k4a*4+0][ra] = av.x;  As[k4a*4+1][ra] = av.y;
        As[k4a*4+2][ra] = av.z;  As[k4a*4+3][ra] = av.w;
        *reinterpret_cast<float4*>(&Bs[kb][c4b*4]) = bv;
        __syncthreads();
        #pragma unroll
        for (int kk = 0; kk < 16; ++kk) {
            float4 a = *reinterpret_cast<const float4*>(&As[kk][tr*4]);
            float4 b = *reinterpret_cast<const float4*>(&Bs[kk][tc*4]);
            float aa[4] = {a.x, a.y, a.z, a.w};
            float bb[4] = {b.x, b.y, b.z, b.w};
            #pragma unroll
            for (int i = 0; i < 4; ++i)
                #pragma unroll
                for (int j = 0; j < 4; ++j)
                    acc[i][j] += aa[i] * bb[j];
        }
    }
    float4 bv = *reinterpret_cast<const float4*>(&bias[col0 + tc*4]);
    #pragma unroll
    for (int i = 0; i < 4; ++i) {
        float4 o;
        o.x = acc[i][0] + bv.x;  o.y = acc[i][1] + bv.y;
        o.z = acc[i][2] + bv.z;  o.w = acc[i][3] + bv.w;
        *reinterpret_cast<float4*>(&out[(size_t)(row0 + tr*4 + i) * Uu + col0 + tc*4]) = o;
    }
}

// ============ Kernel 2: scan1 — r8 VERBATIM (proven through FULL harness) ============
// 256 wgs = 16 groups x 16 members (1 wg/CU — wide residency margin),
// counter barrier, 64 KB LDS, split-bf16 3-term MFMA, Wr register-resident.
__global__ __launch_bounds__(512, 2) void scan_kernel1(
    const float* __restrict__ Wr, const float* __restrict__ h0,
    float* __restrict__ out, unsigned* __restrict__ bar)
{
    __shared__ __align__(16) char hs_hi[16 * 2048];
    __shared__ __align__(16) char hs_lo[16 * 2048];
    float* pl = reinterpret_cast<float*>(hs_hi);      // [4][2][16][17] overlay

    const int tid  = threadIdx.x;
    const int lane = tid & 63;
    const int w    = tid >> 6;
    const int bid  = (int)blockIdx.x;
    const int g    = bid >> 4;
    const int mem  = bid & 15;
    const int b0   = g * 16;
    const int col0 = mem * 64;

    const int ct = w >> 1;
    const int kh = w & 1;
    const int tcol0 = col0 + ct * 16;

    short8v bhi[16], blo[16];
    {
        const int bcol  = tcol0 + (lane & 15);
        const int krow0 = kh * 512 + (lane >> 4) * 8;
        #pragma unroll
        for (int f = 0; f < 16; ++f) {
            short8v rh, rl;
            #pragma unroll
            for (int e = 0; e < 8; ++e) {
                const int k = krow0 + f * 32 + e;
                float v = Wr[(size_t)k * Uu + bcol];
                if (k == bcol) v = 0.f;           // tf.set_diag(..., 0)
                const uint16_t hb = f2bf_bits(v);
                rh[e] = (short)hb;
                rl[e] = (short)f2bf_bits(v - bfbits2f(hb));
            }
            bhi[f] = rh;  blo[f] = rl;
        }
    }

    const int  arow   = lane & 15;
    const int  asw    = (arow & 7) << 4;
    const int  abase  = kh * 1024 + ((lane >> 4) * 16);

    const int srow = tid >> 5;
    const int scb  = (tid & 31) * 64;
    const int ssw  = (srow & 7) << 4;

    const int rs  = tid >> 5;
    const int rc  = (tid & 31) * 2;
    const int rct = rc >> 4;
    const int rcc = rc & 15;

    unsigned* cnt = bar + g * 64;

    for (int t = 0; t < Tt; ++t) {
        float* orow = &out[((size_t)(b0 + rs) * Tt + t) * Uu + col0 + rc];
        float2 xiv = __builtin_bit_cast(float2,
            __builtin_nontemporal_load(reinterpret_cast<const uint64_t*>(orow)));

        {
            const float* src = (t == 0)
                ? (h0 + (size_t)(b0 + srow) * Uu)
                : (out + ((size_t)(b0 + srow) * Tt + (t - 1)) * Uu);
            const int e0 = scb >> 1;
            #pragma unroll
            for (int j = 0; j < 4; ++j) {
                uint64_t a = llc_load_u64(src + e0 + j * 8);
                uint64_t b = llc_load_u64(src + e0 + j * 8 + 2);
                uint64_t c = llc_load_u64(src + e0 + j * 8 + 4);
                uint64_t d = llc_load_u64(src + e0 + j * 8 + 6);
                float2 fa = __builtin_bit_cast(float2, a);
                float2 fb = __builtin_bit_cast(float2, b);
                float2 fc = __builtin_bit_cast(float2, c);
                float2 fd = __builtin_bit_cast(float2, d);
                uint4 qh, ql;
                split2(fa.x, fa.y, qh.x, ql.x);
                split2(fb.x, fb.y, qh.y, ql.y);
                split2(fc.x, fc.y, qh.z, ql.z);
                split2(fd.x, fd.y, qh.w, ql.w);
                const int off = srow * 2048 + ((scb + j * 16) ^ ssw);
                *reinterpret_cast<uint4*>(hs_hi + off) = qh;
                *reinterpret_cast<uint4*>(hs_lo + off) = ql;
            }
        }
        __syncthreads();

        f32x4 a0 = {0.f, 0.f, 0.f, 0.f};
        f32x4 a1 = {0.f, 0.f, 0.f, 0.f};
        f32x4 a2 = {0.f, 0.f, 0.f, 0.f};
        #pragma unroll
        for (int f = 0; f < 16; ++f) {
            const int off = arow * 2048 + ((abase + 64 * f) ^ asw);
            short8v ahi = *reinterpret_cast<const short8v*>(hs_hi + off);
            short8v alo = *reinterpret_cast<const short8v*>(hs_lo + off);
            a0 = __builtin_amdgcn_mfma_f32_16x16x32_bf16(ahi, bhi[f], a0, 0, 0, 0);
            a1 = __builtin_amdgcn_mfma_f32_16x16x32_bf16(alo, bhi[f], a1, 0, 0, 0);
            a2 = __builtin_amdgcn_mfma_f32_16x16x32_bf16(ahi, blo[f], a2, 0, 0, 0);
        }
        const f32x4 accv = (a0 + a1) + a2;

        __syncthreads();

        {
            const int prow0 = (lane >> 4) * 4;
            #pragma unroll
            for (int j = 0; j < 4; ++j)
                pl[(((ct * 2 + kh) * 16) + prow0 + j) * 17 + (lane & 15)] = accv[j];
        }
        __syncthreads();

        {
            const int base0 = ((rct * 2 + 0) * 16 + rs) * 17 + rcc;
            const int base1 = ((rct * 2 + 1) * 16 + rs) * 17 + rcc;
            float v0 = pl[base0]     + pl[base1];
            float v1 = pl[base0 + 1] + pl[base1 + 1];
            float iz0 = xiv.x + v0;
            float iz1 = xiv.y + v1;
            float o0 = iz0 * iz0 - iz0;
            float o1 = iz1 * iz1 - iz1;
            o0 = fminf(fmaxf(o0, -1.f), 1.f);
            o1 = fminf(fmaxf(o1, -1.f), 1.f);
            llc_store_f2(orow, make_float2(o0, o1));
        }

        __syncthreads();
        if (tid == 0) {
            __hip_atomic_fetch_add(cnt, 1u, __ATOMIC_RELAXED, __HIP_MEMORY_SCOPE_AGENT);
            const unsigned target = 16u * (unsigned)(t + 1);
            while (__hip_atomic_load(cnt, __ATOMIC_RELAXED, __HIP_MEMORY_SCOPE_AGENT) < target)
                __builtin_amdgcn_s_sleep(2);
        }
        __syncthreads();
    }
}

extern "C" void kernel_launch(void* const* d_in, const int* in_sizes, int n_in,
                              void* d_out, int out_size, void* d_ws, size_t ws_size,
                              hipStream_t stream) {
    const float* x  = (const float*)d_in[0];
    const float* h0 = (const float*)d_in[1];
    const float* Wi = (const float*)d_in[2];
    const float* b  = (const float*)d_in[3];
    const float* Wr = (const float*)d_in[4];
    float* out = (float*)d_out;

    unsigned* bar = (unsigned*)d_ws;                       // 4 KB counters
    const size_t wit_bytes = (size_t)Uu * Dd * 2;          // 1 MB each
    uint16_t* WiT_hi = (uint16_t*)((char*)d_ws + 8192);
    uint16_t* WiT_lo = (uint16_t*)((char*)d_ws + 8192 + wit_bytes);
    const bool ws_ok = ws_size >= 8192 + 2 * wit_bytes;

    init_bar_kernel<<<1, 1024, 0, stream>>>(bar);

    if (ws_ok) {
        wi_split_kernel<<<dim3(Dd / 32, Uu / 32), 256, 0, stream>>>(Wi, WiT_hi, WiT_lo);
        xi_mfma_kernel<<<dim3((Bb * Tt) / 64, Uu / 256), 512, 0, stream>>>(
            x, WiT_hi, WiT_lo, b, out);
    } else {
        xi_gemm_kernel<<<dim3((Bb * Tt) / 64, Uu / 64), 256, 0, stream>>>(x, Wi, b, out);
    }

    // scan: r8-proven config, unconditional (256 blocks = 1 wg/CU, wide margin)
    void* args[] = { (void*)&Wr, (void*)&h0, (void*)&out, (void*)&bar };
    hipLaunchCooperativeKernel((const void*)scan_kernel1, dim3(256), dim3(512),
                               args, 0, stream);
}

// Round 17
// 847.905 us; speedup vs baseline: 12.6198x; 1.7493x over previous
//
#include <hip/hip_runtime.h>
#include <hip/hip_bf16.h>
#include <cstdint>

#define Bb 256
#define Tt 128
#define Dd 512
#define Uu 1024

typedef __attribute__((ext_vector_type(8))) short short8v;  // 8 bf16 = 4 VGPRs
typedef __attribute__((ext_vector_type(4))) float f32x4;

// ---------------- init: zero barrier storage ----------------
__global__ void init_bar_kernel(unsigned* __restrict__ bar) {
    bar[threadIdx.x] = 0u;    // 1024 uints = 4 KB (covers counters at g*64)
}

// ---------------- LLC-coherent (fence-free device-scope) primitives ----------------
__device__ __forceinline__ uint64_t llc_load_u64(const void* p) {
    return __hip_atomic_load((const uint64_t*)p, __ATOMIC_RELAXED,
                             __HIP_MEMORY_SCOPE_AGENT);
}
__device__ __forceinline__ void llc_store_f2(float* p, float2 v) {
    __hip_atomic_store((uint64_t*)p, __builtin_bit_cast(uint64_t, v),
                       __ATOMIC_RELAXED, __HIP_MEMORY_SCOPE_AGENT);
}

__device__ __forceinline__ uint16_t f2bf_bits(float x) {
    union { __hip_bfloat16 h; uint16_t u; } c;
    c.h = __float2bfloat16(x);
    return c.u;
}
__device__ __forceinline__ float bfbits2f(uint16_t b) {
    uint32_t u = ((uint32_t)b) << 16;
    return __builtin_bit_cast(float, u);
}
__device__ __forceinline__ void split2(float x, float y, uint32_t& hi, uint32_t& lo) {
    const uint16_t hx = f2bf_bits(x), hy = f2bf_bits(y);
    const uint16_t lx = f2bf_bits(x - bfbits2f(hx));
    const uint16_t ly = f2bf_bits(y - bfbits2f(hy));
    hi = (uint32_t)hx | ((uint32_t)hy << 16);
    lo = (uint32_t)lx | ((uint32_t)ly << 16);
}

// ---------------- Wi transpose+split: WiT_hi/lo[c][k] bf16, k-contiguous ----------
// tile stride 36 floats = 144 B (multiple of 16) -> aligned float4 LDS stores.
__global__ __launch_bounds__(256, 4) void wi_split_kernel(
    const float* __restrict__ Wi, uint16_t* __restrict__ WiT_hi,
    uint16_t* __restrict__ WiT_lo)
{
    __shared__ float tile[32][36];
    const int k0 = blockIdx.x * 32;
    const int c0 = blockIdx.y * 32;
    {
        const int r  = threadIdx.x >> 3;
        const int c4 = (threadIdx.x & 7) * 4;
        *reinterpret_cast<float4*>(&tile[r][c4]) =
            *reinterpret_cast<const float4*>(&Wi[(size_t)(k0 + r) * Uu + c0 + c4]);
    }
    __syncthreads();
    {
        const int c  = threadIdx.x >> 3;
        const int k4 = (threadIdx.x & 7) * 4;
        uint16_t h[4], l[4];
        #pragma unroll
        for (int i = 0; i < 4; ++i) {
            float v = tile[k4 + i][c];
            h[i] = f2bf_bits(v);
            l[i] = f2bf_bits(v - bfbits2f(h[i]));
        }
        uint64_t hp = (uint64_t)h[0] | ((uint64_t)h[1] << 16)
                    | ((uint64_t)h[2] << 32) | ((uint64_t)h[3] << 48);
        uint64_t lp = (uint64_t)l[0] | ((uint64_t)l[1] << 16)
                    | ((uint64_t)l[2] << 32) | ((uint64_t)l[3] << 48);
        const size_t off = (size_t)(c0 + c) * Dd + k0 + k4;
        *reinterpret_cast<uint64_t*>(&WiT_hi[off]) = hp;
        *reinterpret_cast<uint64_t*>(&WiT_lo[off]) = lp;
    }
}

// ---------------- xi = x @ Wi + b via split-bf16 MFMA (r15-proven) ----------------
__global__ __launch_bounds__(512, 4) void xi_mfma_kernel(
    const float* __restrict__ x, const uint16_t* __restrict__ WiT_hi,
    const uint16_t* __restrict__ WiT_lo, const float* __restrict__ bias,
    float* __restrict__ out)
{
    __shared__ __align__(16) char xs_hi[64 * 128];
    __shared__ __align__(16) char xs_lo[64 * 128];

    const int tid  = threadIdx.x;
    const int lane = tid & 63;
    const int nq   = tid >> 6;
    const int rowb = blockIdx.x * 64;
    const int colw = blockIdx.y * 256 + nq * 32;

    const int sr  = tid >> 3;
    const int k8  = (tid & 7) * 8;
    const int ssw = (sr & 7) << 4;

    const int arow_l = lane & 15;
    const int akl    = (lane >> 4) * 16;
    const int kl     = (lane >> 4) * 8;

    const uint16_t* wh[2];
    const uint16_t* wl[2];
    float bv[2];
    #pragma unroll
    for (int nt = 0; nt < 2; ++nt) {
        const int c = colw + nt * 16 + arow_l;
        wh[nt] = WiT_hi + (size_t)c * Dd;
        wl[nt] = WiT_lo + (size_t)c * Dd;
        bv[nt] = bias[c];
    }

    f32x4 acc[4][2];
    #pragma unroll
    for (int mt = 0; mt < 4; ++mt)
        #pragma unroll
        for (int nt = 0; nt < 2; ++nt)
            acc[mt][nt] = (f32x4){0.f, 0.f, 0.f, 0.f};

    for (int k0 = 0; k0 < Dd; k0 += 64) {
        {
            const float* src = &x[(size_t)(rowb + sr) * Dd + k0 + k8];
            float4 a = *reinterpret_cast<const float4*>(src);
            float4 b = *reinterpret_cast<const float4*>(src + 4);
            uint4 qh, ql;
            split2(a.x, a.y, qh.x, ql.x);
            split2(a.z, a.w, qh.y, ql.y);
            split2(b.x, b.y, qh.z, ql.z);
            split2(b.z, b.w, qh.w, ql.w);
            const int off = sr * 128 + ((k8 * 2) ^ ssw);
            *reinterpret_cast<uint4*>(xs_hi + off) = qh;
            *reinterpret_cast<uint4*>(xs_lo + off) = ql;
        }
        __syncthreads();

        #pragma unroll
        for (int fl = 0; fl < 2; ++fl) {
            short8v bh[2], bl[2];
            #pragma unroll
            for (int nt = 0; nt < 2; ++nt) {
                const int kb = k0 + fl * 32 + kl;
                bh[nt] = *reinterpret_cast<const short8v*>(wh[nt] + kb);
                bl[nt] = *reinterpret_cast<const short8v*>(wl[nt] + kb);
            }
            #pragma unroll
            for (int mt = 0; mt < 4; ++mt) {
                const int row = mt * 16 + arow_l;
                const int off = row * 128 + ((fl * 64 + akl) ^ ((row & 7) << 4));
                short8v ah = *reinterpret_cast<const short8v*>(xs_hi + off);
                short8v al = *reinterpret_cast<const short8v*>(xs_lo + off);
                #pragma unroll
                for (int nt = 0; nt < 2; ++nt) {
                    acc[mt][nt] = __builtin_amdgcn_mfma_f32_16x16x32_bf16(ah, bh[nt], acc[mt][nt], 0, 0, 0);
                    acc[mt][nt] = __builtin_amdgcn_mfma_f32_16x16x32_bf16(al, bh[nt], acc[mt][nt], 0, 0, 0);
                    acc[mt][nt] = __builtin_amdgcn_mfma_f32_16x16x32_bf16(ah, bl[nt], acc[mt][nt], 0, 0, 0);
                }
            }
        }
        __syncthreads();
    }

    const int prow = (lane >> 4) * 4;
    #pragma unroll
    for (int mt = 0; mt < 4; ++mt)
        #pragma unroll
        for (int nt = 0; nt < 2; ++nt)
            #pragma unroll
            for (int j = 0; j < 4; ++j)
                out[(size_t)(rowb + mt * 16 + prow + j) * Uu + colw + nt * 16 + arow_l]
                    = acc[mt][nt][j] + bv[nt];
}

// ---------------- FALLBACK xi (f32 VALU, proven) ----------------
__global__ __launch_bounds__(256, 1) void xi_gemm_kernel(
    const float* __restrict__ x, const float* __restrict__ Wi,
    const float* __restrict__ bias, float* __restrict__ out)
{
    __shared__ __align__(16) float As[16][64];
    __shared__ __align__(16) float Bs[16][64];
    const int tid  = threadIdx.x;
    const int row0 = blockIdx.x * 64;
    const int col0 = blockIdx.y * 64;
    const int tr = tid >> 4, tc = tid & 15;
    const int ra = tid & 63, k4a = tid >> 6, kb = tid >> 4, c4b = tid & 15;
    float acc[4][4] = {};
    for (int k0 = 0; k0 < Dd; k0 += 16) {
        float4 av = *reinterpret_cast<const float4*>(&x[(size_t)(row0 + ra) * Dd + k0 + k4a * 4]);
        float4 bv = *reinterpret_cast<const float4*>(&Wi[(size_t)(k0 + kb) * Uu + col0 + c4b * 4]);
        __syncthreads();
        As[k4a*4+0][ra] = av.x;  As[k4a*4+1][ra] = av.y;
        As[k4a*4+2][ra] = av.z;  As[k4a*4+3][ra] = av.w;
        *reinterpret_cast<float4*>(&Bs[kb][c4b*4]) = bv;
        __syncthreads();
        #pragma unroll
        for (int kk = 0; kk < 16; ++kk) {
            float4 a = *reinterpret_cast<const float4*>(&As[kk][tr*4]);
            float4 b = *reinterpret_cast<const float4*>(&Bs[kk][tc*4]);
            float aa[4] = {a.x, a.y, a.z, a.w};
            float bb[4] = {b.x, b.y, b.z, b.w};
            #pragma unroll
            for (int i = 0; i < 4; ++i)
                #pragma unroll
                for (int j = 0; j < 4; ++j)
                    acc[i][j] += aa[i] * bb[j];
        }
    }
    float4 bv = *reinterpret_cast<const float4*>(&bias[col0 + tc*4]);
    #pragma unroll
    for (int i = 0; i < 4; ++i) {
        float4 o;
        o.x = acc[i][0] + bv.x;  o.y = acc[i][1] + bv.y;
        o.z = acc[i][2] + bv.z;  o.w = acc[i][3] + bv.w;
        *reinterpret_cast<float4*>(&out[(size_t)(row0 + tr*4 + i) * Uu + col0 + tc*4]) = o;
    }
}

// ============ Kernel 2: scan1 — r15 verbatim EXCEPT staging thread->chunk map ============
// 256 wgs = 16 groups x 16 members (1 wg/CU), counter barrier (byte-identical
// to r8/r15, proven replay-safe). ONLY r17 change: staging chunk assignment
// kb = l5*16 + j*512 (lane-contiguous 16B writes, conflict-free — this exact
// pattern passed the full harness inside r10's scan2). Same bytes to same
// physical (swizzled) addresses; only which THREAD writes which chunk changes.
__global__ __launch_bounds__(512, 2) void scan_kernel1(
    const float* __restrict__ Wr, const float* __restrict__ h0,
    float* __restrict__ out, unsigned* __restrict__ bar)
{
    __shared__ __align__(16) char hs_hi[16 * 2048];
    __shared__ __align__(16) char hs_lo[16 * 2048];
    float* pl = reinterpret_cast<float*>(hs_hi);      // [4][2][16][17] overlay

    const int tid  = threadIdx.x;
    const int lane = tid & 63;
    const int w    = tid >> 6;
    const int bid  = (int)blockIdx.x;
    const int g    = bid >> 4;
    const int mem  = bid & 15;
    const int b0   = g * 16;
    const int col0 = mem * 64;

    const int ct = w >> 1;
    const int kh = w & 1;
    const int tcol0 = col0 + ct * 16;

    short8v bhi[16], blo[16];
    {
        const int bcol  = tcol0 + (lane & 15);
        const int krow0 = kh * 512 + (lane >> 4) * 8;
        #pragma unroll
        for (int f = 0; f < 16; ++f) {
            short8v rh, rl;
            #pragma unroll
            for (int e = 0; e < 8; ++e) {
                const int k = krow0 + f * 32 + e;
                float v = Wr[(size_t)k * Uu + bcol];
                if (k == bcol) v = 0.f;           // tf.set_diag(..., 0)
                const uint16_t hb = f2bf_bits(v);
                rh[e] = (short)hb;
                rl[e] = (short)f2bf_bits(v - bfbits2f(hb));
            }
            bhi[f] = rh;  blo[f] = rl;
        }
    }

    const int  arow   = lane & 15;
    const int  asw    = (arow & 7) << 4;
    const int  abase  = kh * 1024 + ((lane >> 4) * 16);

    const int srow = tid >> 5;          // 0..15
    const int l5   = tid & 31;          // 0..31
    const int ssw  = (srow & 7) << 4;

    const int rs  = tid >> 5;
    const int rc  = (tid & 31) * 2;
    const int rct = rc >> 4;
    const int rcc = rc & 15;

    unsigned* cnt = bar + g * 64;

    for (int t = 0; t < Tt; ++t) {
        float* orow = &out[((size_t)(b0 + rs) * Tt + t) * Uu + col0 + rc];
        float2 xiv = __builtin_bit_cast(float2,
            __builtin_nontemporal_load(reinterpret_cast<const uint64_t*>(orow)));

        // ---- stage h[16][1024] f32 -> split bf16 hi/lo (conflict-free map) ----
        {
            const float* src = (t == 0)
                ? (h0 + (size_t)(b0 + srow) * Uu)
                : (out + ((size_t)(b0 + srow) * Tt + (t - 1)) * Uu);
            #pragma unroll
            for (int j = 0; j < 4; ++j) {
                const int kb = l5 * 16 + j * 512;   // byte in 2048B bf16 row
                const int e0 = kb >> 1;             // 8 f32 elements
                uint64_t a = llc_load_u64(src + e0);
                uint64_t b = llc_load_u64(src + e0 + 2);
                uint64_t c = llc_load_u64(src + e0 + 4);
                uint64_t d = llc_load_u64(src + e0 + 6);
                float2 fa = __builtin_bit_cast(float2, a);
                float2 fb = __builtin_bit_cast(float2, b);
                float2 fc = __builtin_bit_cast(float2, c);
                float2 fd = __builtin_bit_cast(float2, d);
                uint4 qh, ql;
                split2(fa.x, fa.y, qh.x, ql.x);
                split2(fb.x, fb.y, qh.y, ql.y);
                split2(fc.x, fc.y, qh.z, ql.z);
                split2(fd.x, fd.y, qh.w, ql.w);
                const int off = srow * 2048 + (kb ^ ssw);
                *reinterpret_cast<uint4*>(hs_hi + off) = qh;
                *reinterpret_cast<uint4*>(hs_lo + off) = ql;
            }
        }
        __syncthreads();

        f32x4 a0 = {0.f, 0.f, 0.f, 0.f};
        f32x4 a1 = {0.f, 0.f, 0.f, 0.f};
        f32x4 a2 = {0.f, 0.f, 0.f, 0.f};
        #pragma unroll
        for (int f = 0; f < 16; ++f) {
            const int off = arow * 2048 + ((abase + 64 * f) ^ asw);
            short8v ahi = *reinterpret_cast<const short8v*>(hs_hi + off);
            short8v alo = *reinterpret_cast<const short8v*>(hs_lo + off);
            a0 = __builtin_amdgcn_mfma_f32_16x16x32_bf16(ahi, bhi[f], a0, 0, 0, 0);
            a1 = __builtin_amdgcn_mfma_f32_16x16x32_bf16(alo, bhi[f], a1, 0, 0, 0);
            a2 = __builtin_amdgcn_mfma_f32_16x16x32_bf16(ahi, blo[f], a2, 0, 0, 0);
        }
        const f32x4 accv = (a0 + a1) + a2;

        __syncthreads();   // all waves done READING hs_hi before pl overlays it

        {
            const int prow0 = (lane >> 4) * 4;
            #pragma unroll
            for (int j = 0; j < 4; ++j)
                pl[(((ct * 2 + kh) * 16) + prow0 + j) * 17 + (lane & 15)] = accv[j];
        }
        __syncthreads();

        {
            const int base0 = ((rct * 2 + 0) * 16 + rs) * 17 + rcc;
            const int base1 = ((rct * 2 + 1) * 16 + rs) * 17 + rcc;
            float v0 = pl[base0]     + pl[base1];
            float v1 = pl[base0 + 1] + pl[base1 + 1];
            float iz0 = xiv.x + v0;
            float iz1 = xiv.y + v1;
            float o0 = iz0 * iz0 - iz0;
            float o1 = iz1 * iz1 - iz1;
            o0 = fminf(fmaxf(o0, -1.f), 1.f);
            o1 = fminf(fmaxf(o1, -1.f), 1.f);
            llc_store_f2(orow, make_float2(o0, o1));
        }

        __syncthreads();
        if (tid == 0) {
            __hip_atomic_fetch_add(cnt, 1u, __ATOMIC_RELAXED, __HIP_MEMORY_SCOPE_AGENT);
            const unsigned target = 16u * (unsigned)(t + 1);
            while (__hip_atomic_load(cnt, __ATOMIC_RELAXED, __HIP_MEMORY_SCOPE_AGENT) < target)
                __builtin_amdgcn_s_sleep(2);
        }
        __syncthreads();
    }
}

extern "C" void kernel_launch(void* const* d_in, const int* in_sizes, int n_in,
                              void* d_out, int out_size, void* d_ws, size_t ws_size,
                              hipStream_t stream) {
    const float* x  = (const float*)d_in[0];
    const float* h0 = (const float*)d_in[1];
    const float* Wi = (const float*)d_in[2];
    const float* b  = (const float*)d_in[3];
    const float* Wr = (const float*)d_in[4];
    float* out = (float*)d_out;

    unsigned* bar = (unsigned*)d_ws;                       // 4 KB counters
    const size_t wit_bytes = (size_t)Uu * Dd * 2;          // 1 MB each
    uint16_t* WiT_hi = (uint16_t*)((char*)d_ws + 8192);
    uint16_t* WiT_lo = (uint16_t*)((char*)d_ws + 8192 + wit_bytes);
    const bool ws_ok = ws_size >= 8192 + 2 * wit_bytes;

    init_bar_kernel<<<1, 1024, 0, stream>>>(bar);

    if (ws_ok) {
        wi_split_kernel<<<dim3(Dd / 32, Uu / 32), 256, 0, stream>>>(Wi, WiT_hi, WiT_lo);
        xi_mfma_kernel<<<dim3((Bb * Tt) / 64, Uu / 256), 512, 0, stream>>>(
            x, WiT_hi, WiT_lo, b, out);
    } else {
        xi_gemm_kernel<<<dim3((Bb * Tt) / 64, Uu / 64), 256, 0, stream>>>(x, Wi, b, out);
    }

    // scan: r8-proven config, unconditional (256 blocks = 1 wg/CU, wide margin)
    void* args[] = { (void*)&Wr, (void*)&h0, (void*)&out, (void*)&bar };
    hipLaunchCooperativeKernel((const void*)scan_kernel1, dim3(256), dim3(512),
                               args, 0, stream);
}

// Round 19
// 836.987 us; speedup vs baseline: 12.7844x; 1.0130x over previous
//
#include <hip/hip_runtime.h>
#include <hip/hip_bf16.h>
#include <cstdint>

#define Bb 256
#define Tt 128
#define Dd 512
#define Uu 1024

typedef __attribute__((ext_vector_type(8))) short short8v;  // 8 bf16 = 4 VGPRs
typedef __attribute__((ext_vector_type(4))) float f32x4;

// ---------------- init: zero barrier storage ----------------
__global__ void init_bar_kernel(unsigned* __restrict__ bar) {
    bar[threadIdx.x] = 0u;    // 1024 uints = 4 KB (covers counters at g*64)
}

// ---------------- LLC-coherent (fence-free device-scope) primitives ----------------
__device__ __forceinline__ uint64_t llc_load_u64(const void* p) {
    return __hip_atomic_load((const uint64_t*)p, __ATOMIC_RELAXED,
                             __HIP_MEMORY_SCOPE_AGENT);
}
__device__ __forceinline__ void llc_store_f2(float* p, float2 v) {
    __hip_atomic_store((uint64_t*)p, __builtin_bit_cast(uint64_t, v),
                       __ATOMIC_RELAXED, __HIP_MEMORY_SCOPE_AGENT);
}

__device__ __forceinline__ uint16_t f2bf_bits(float x) {
    union { __hip_bfloat16 h; uint16_t u; } c;
    c.h = __float2bfloat16(x);
    return c.u;
}
__device__ __forceinline__ float bfbits2f(uint16_t b) {
    uint32_t u = ((uint32_t)b) << 16;
    return __builtin_bit_cast(float, u);
}
__device__ __forceinline__ void split2(float x, float y, uint32_t& hi, uint32_t& lo) {
    const uint16_t hx = f2bf_bits(x), hy = f2bf_bits(y);
    const uint16_t lx = f2bf_bits(x - bfbits2f(hx));
    const uint16_t ly = f2bf_bits(y - bfbits2f(hy));
    hi = (uint32_t)hx | ((uint32_t)hy << 16);
    lo = (uint32_t)lx | ((uint32_t)ly << 16);
}

// ---------------- Wi transpose+split: WiT_hi/lo[c][k] bf16, k-contiguous ----------
// tile stride 36 floats = 144 B (multiple of 16) -> aligned float4 LDS stores.
__global__ __launch_bounds__(256, 4) void wi_split_kernel(
    const float* __restrict__ Wi, uint16_t* __restrict__ WiT_hi,
    uint16_t* __restrict__ WiT_lo)
{
    __shared__ float tile[32][36];
    const int k0 = blockIdx.x * 32;
    const int c0 = blockIdx.y * 32;
    {
        const int r  = threadIdx.x >> 3;
        const int c4 = (threadIdx.x & 7) * 4;
        *reinterpret_cast<float4*>(&tile[r][c4]) =
            *reinterpret_cast<const float4*>(&Wi[(size_t)(k0 + r) * Uu + c0 + c4]);
    }
    __syncthreads();
    {
        const int c  = threadIdx.x >> 3;
        const int k4 = (threadIdx.x & 7) * 4;
        uint16_t h[4], l[4];
        #pragma unroll
        for (int i = 0; i < 4; ++i) {
            float v = tile[k4 + i][c];
            h[i] = f2bf_bits(v);
            l[i] = f2bf_bits(v - bfbits2f(h[i]));
        }
        uint64_t hp = (uint64_t)h[0] | ((uint64_t)h[1] << 16)
                    | ((uint64_t)h[2] << 32) | ((uint64_t)h[3] << 48);
        uint64_t lp = (uint64_t)l[0] | ((uint64_t)l[1] << 16)
                    | ((uint64_t)l[2] << 32) | ((uint64_t)l[3] << 48);
        const size_t off = (size_t)(c0 + c) * Dd + k0 + k4;
        *reinterpret_cast<uint64_t*>(&WiT_hi[off]) = hp;
        *reinterpret_cast<uint64_t*>(&WiT_lo[off]) = lp;
    }
}

// ---------------- xi = x @ Wi + b via split-bf16 MFMA (r15/r17-proven) ----------------
__global__ __launch_bounds__(512, 4) void xi_mfma_kernel(
    const float* __restrict__ x, const uint16_t* __restrict__ WiT_hi,
    const uint16_t* __restrict__ WiT_lo, const float* __restrict__ bias,
    float* __restrict__ out)
{
    __shared__ __align__(16) char xs_hi[64 * 128];
    __shared__ __align__(16) char xs_lo[64 * 128];

    const int tid  = threadIdx.x;
    const int lane = tid & 63;
    const int nq   = tid >> 6;
    const int rowb = blockIdx.x * 64;
    const int colw = blockIdx.y * 256 + nq * 32;

    const int sr  = tid >> 3;
    const int k8  = (tid & 7) * 8;
    const int ssw = (sr & 7) << 4;

    const int arow_l = lane & 15;
    const int akl    = (lane >> 4) * 16;
    const int kl     = (lane >> 4) * 8;

    const uint16_t* wh[2];
    const uint16_t* wl[2];
    float bv[2];
    #pragma unroll
    for (int nt = 0; nt < 2; ++nt) {
        const int c = colw + nt * 16 + arow_l;
        wh[nt] = WiT_hi + (size_t)c * Dd;
        wl[nt] = WiT_lo + (size_t)c * Dd;
        bv[nt] = bias[c];
    }

    f32x4 acc[4][2];
    #pragma unroll
    for (int mt = 0; mt < 4; ++mt)
        #pragma unroll
        for (int nt = 0; nt < 2; ++nt)
            acc[mt][nt] = (f32x4){0.f, 0.f, 0.f, 0.f};

    for (int k0 = 0; k0 < Dd; k0 += 64) {
        {
            const float* src = &x[(size_t)(rowb + sr) * Dd + k0 + k8];
            float4 a = *reinterpret_cast<const float4*>(src);
            float4 b = *reinterpret_cast<const float4*>(src + 4);
            uint4 qh, ql;
            split2(a.x, a.y, qh.x, ql.x);
            split2(a.z, a.w, qh.y, ql.y);
            split2(b.x, b.y, qh.z, ql.z);
            split2(b.z, b.w, qh.w, ql.w);
            const int off = sr * 128 + ((k8 * 2) ^ ssw);
            *reinterpret_cast<uint4*>(xs_hi + off) = qh;
            *reinterpret_cast<uint4*>(xs_lo + off) = ql;
        }
        __syncthreads();

        #pragma unroll
        for (int fl = 0; fl < 2; ++fl) {
            short8v bh[2], bl[2];
            #pragma unroll
            for (int nt = 0; nt < 2; ++nt) {
                const int kb = k0 + fl * 32 + kl;
                bh[nt] = *reinterpret_cast<const short8v*>(wh[nt] + kb);
                bl[nt] = *reinterpret_cast<const short8v*>(wl[nt] + kb);
            }
            #pragma unroll
            for (int mt = 0; mt < 4; ++mt) {
                const int row = mt * 16 + arow_l;
                const int off = row * 128 + ((fl * 64 + akl) ^ ((row & 7) << 4));
                short8v ah = *reinterpret_cast<const short8v*>(xs_hi + off);
                short8v al = *reinterpret_cast<const short8v*>(xs_lo + off);
                #pragma unroll
                for (int nt = 0; nt < 2; ++nt) {
                    acc[mt][nt] = __builtin_amdgcn_mfma_f32_16x16x32_bf16(ah, bh[nt], acc[mt][nt], 0, 0, 0);
                    acc[mt][nt] = __builtin_amdgcn_mfma_f32_16x16x32_bf16(al, bh[nt], acc[mt][nt], 0, 0, 0);
                    acc[mt][nt] = __builtin_amdgcn_mfma_f32_16x16x32_bf16(ah, bl[nt], acc[mt][nt], 0, 0, 0);
                }
            }
        }
        __syncthreads();
    }

    const int prow = (lane >> 4) * 4;
    #pragma unroll
    for (int mt = 0; mt < 4; ++mt)
        #pragma unroll
        for (int nt = 0; nt < 2; ++nt)
            #pragma unroll
            for (int j = 0; j < 4; ++j)
                out[(size_t)(rowb + mt * 16 + prow + j) * Uu + colw + nt * 16 + arow_l]
                    = acc[mt][nt][j] + bv[nt];
}

// ---------------- FALLBACK xi (f32 VALU, proven) ----------------
__global__ __launch_bounds__(256, 1) void xi_gemm_kernel(
    const float* __restrict__ x, const float* __restrict__ Wi,
    const float* __restrict__ bias, float* __restrict__ out)
{
    __shared__ __align__(16) float As[16][64];
    __shared__ __align__(16) float Bs[16][64];
    const int tid  = threadIdx.x;
    const int row0 = blockIdx.x * 64;
    const int col0 = blockIdx.y * 64;
    const int tr = tid >> 4, tc = tid & 15;
    const int ra = tid & 63, k4a = tid >> 6, kb = tid >> 4, c4b = tid & 15;
    float acc[4][4] = {};
    for (int k0 = 0; k0 < Dd; k0 += 16) {
        float4 av = *reinterpret_cast<const float4*>(&x[(size_t)(row0 + ra) * Dd + k0 + k4a * 4]);
        float4 bv = *reinterpret_cast<const float4*>(&Wi[(size_t)(k0 + kb) * Uu + col0 + c4b * 4]);
        __syncthreads();
        As[k4a*4+0][ra] = av.x;  As[k4a*4+1][ra] = av.y;
        As[k4a*4+2][ra] = av.z;  As[k4a*4+3][ra] = av.w;
        *reinterpret_cast<float4*>(&Bs[kb][c4b*4]) = bv;
        __syncthreads();
        #pragma unroll
        for (int kk = 0; kk < 16; ++kk) {
            float4 a = *reinterpret_cast<const float4*>(&As[kk][tr*4]);
            float4 b = *reinterpret_cast<const float4*>(&Bs[kk][tc*4]);
            float aa[4] = {a.x, a.y, a.z, a.w};
            float bb[4] = {b.x, b.y, b.z, b.w};
            #pragma unroll
            for (int i = 0; i < 4; ++i)
                #pragma unroll
                for (int j = 0; j < 4; ++j)
                    acc[i][j] += aa[i] * bb[j];
        }
    }
    float4 bv = *reinterpret_cast<const float4*>(&bias[col0 + tc*4]);
    #pragma unroll
    for (int i = 0; i < 4; ++i) {
        float4 o;
        o.x = acc[i][0] + bv.x;  o.y = acc[i][1] + bv.y;
        o.z = acc[i][2] + bv.z;  o.w = acc[i][3] + bv.w;
        *reinterpret_cast<float4*>(&out[(size_t)(row0 + tr*4 + i) * Uu + col0 + tc*4]) = o;
    }
}

// ============ Kernel 2: scan1 — r17 verbatim (proven: 706 us scan, full harness) ============
// 256 wgs = 16 groups x 16 members (1 wg/CU), serialized-RMW counter barrier
// (the ONLY barrier signal that has never raced: 6/6 full-harness passes).
// Staging: lane-contiguous conflict-free map (r17's +2x win).
__global__ __launch_bounds__(512, 2) void scan_kernel1(
    const float* __restrict__ Wr, const float* __restrict__ h0,
    float* __restrict__ out, unsigned* __restrict__ bar)
{
    __shared__ __align__(16) char hs_hi[16 * 2048];
    __shared__ __align__(16) char hs_lo[16 * 2048];
    float* pl = reinterpret_cast<float*>(hs_hi);      // [4][2][16][17] overlay

    const int tid  = threadIdx.x;
    const int lane = tid & 63;
    const int w    = tid >> 6;
    const int bid  = (int)blockIdx.x;
    const int g    = bid >> 4;
    const int mem  = bid & 15;
    const int b0   = g * 16;
    const int col0 = mem * 64;

    const int ct = w >> 1;
    const int kh = w & 1;
    const int tcol0 = col0 + ct * 16;

    short8v bhi[16], blo[16];
    {
        const int bcol  = tcol0 + (lane & 15);
        const int krow0 = kh * 512 + (lane >> 4) * 8;
        #pragma unroll
        for (int f = 0; f < 16; ++f) {
            short8v rh, rl;
            #pragma unroll
            for (int e = 0; e < 8; ++e) {
                const int k = krow0 + f * 32 + e;
                float v = Wr[(size_t)k * Uu + bcol];
                if (k == bcol) v = 0.f;           // tf.set_diag(..., 0)
                const uint16_t hb = f2bf_bits(v);
                rh[e] = (short)hb;
                rl[e] = (short)f2bf_bits(v - bfbits2f(hb));
            }
            bhi[f] = rh;  blo[f] = rl;
        }
    }

    const int  arow   = lane & 15;
    const int  asw    = (arow & 7) << 4;
    const int  abase  = kh * 1024 + ((lane >> 4) * 16);

    const int srow = tid >> 5;          // 0..15
    const int l5   = tid & 31;          // 0..31
    const int ssw  = (srow & 7) << 4;

    const int rs  = tid >> 5;
    const int rc  = (tid & 31) * 2;
    const int rct = rc >> 4;
    const int rcc = rc & 15;

    unsigned* cnt = bar + g * 64;

    for (int t = 0; t < Tt; ++t) {
        float* orow = &out[((size_t)(b0 + rs) * Tt + t) * Uu + col0 + rc];
        float2 xiv = __builtin_bit_cast(float2,
            __builtin_nontemporal_load(reinterpret_cast<const uint64_t*>(orow)));

        // ---- stage h[16][1024] f32 -> split bf16 hi/lo (conflict-free map) ----
        {
            const float* src = (t == 0)
                ? (h0 + (size_t)(b0 + srow) * Uu)
                : (out + ((size_t)(b0 + srow) * Tt + (t - 1)) * Uu);
            #pragma unroll
            for (int j = 0; j < 4; ++j) {
                const int kb = l5 * 16 + j * 512;   // byte in 2048B bf16 row
                const int e0 = kb >> 1;             // 8 f32 elements
                uint64_t a = llc_load_u64(src + e0);
                uint64_t b = llc_load_u64(src + e0 + 2);
                uint64_t c = llc_load_u64(src + e0 + 4);
                uint64_t d = llc_load_u64(src + e0 + 6);
                float2 fa = __builtin_bit_cast(float2, a);
                float2 fb = __builtin_bit_cast(float2, b);
                float2 fc = __builtin_bit_cast(float2, c);
                float2 fd = __builtin_bit_cast(float2, d);
                uint4 qh, ql;
                split2(fa.x, fa.y, qh.x, ql.x);
                split2(fb.x, fb.y, qh.y, ql.y);
                split2(fc.x, fc.y, qh.z, ql.z);
                split2(fd.x, fd.y, qh.w, ql.w);
                const int off = srow * 2048 + (kb ^ ssw);
                *reinterpret_cast<uint4*>(hs_hi + off) = qh;
                *reinterpret_cast<uint4*>(hs_lo + off) = ql;
            }
        }
        __syncthreads();

        f32x4 a0 = {0.f, 0.f, 0.f, 0.f};
        f32x4 a1 = {0.f, 0.f, 0.f, 0.f};
        f32x4 a2 = {0.f, 0.f, 0.f, 0.f};
        #pragma unroll
        for (int f = 0; f < 16; ++f) {
            const int off = arow * 2048 + ((abase + 64 * f) ^ asw);
            short8v ahi = *reinterpret_cast<const short8v*>(hs_hi + off);
            short8v alo = *reinterpret_cast<const short8v*>(hs_lo + off);
            a0 = __builtin_amdgcn_mfma_f32_16x16x32_bf16(ahi, bhi[f], a0, 0, 0, 0);
            a1 = __builtin_amdgcn_mfma_f32_16x16x32_bf16(alo, bhi[f], a1, 0, 0, 0);
            a2 = __builtin_amdgcn_mfma_f32_16x16x32_bf16(ahi, blo[f], a2, 0, 0, 0);
        }
        const f32x4 accv = (a0 + a1) + a2;

        __syncthreads();   // all waves done READING hs_hi before pl overlays it

        {
            const int prow0 = (lane >> 4) * 4;
            #pragma unroll
            for (int j = 0; j < 4; ++j)
                pl[(((ct * 2 + kh) * 16) + prow0 + j) * 17 + (lane & 15)] = accv[j];
        }
        __syncthreads();

        {
            const int base0 = ((rct * 2 + 0) * 16 + rs) * 17 + rcc;
            const int base1 = ((rct * 2 + 1) * 16 + rs) * 17 + rcc;
            float v0 = pl[base0]     + pl[base1];
            float v1 = pl[base0 + 1] + pl[base1 + 1];
            float iz0 = xiv.x + v0;
            float iz1 = xiv.y + v1;
            float o0 = iz0 * iz0 - iz0;
            float o1 = iz1 * iz1 - iz1;
            o0 = fminf(fmaxf(o0, -1.f), 1.f);
            o1 = fminf(fmaxf(o1, -1.f), 1.f);
            llc_store_f2(orow, make_float2(o0, o1));
        }

        __syncthreads();
        if (tid == 0) {
            __hip_atomic_fetch_add(cnt, 1u, __ATOMIC_RELAXED, __HIP_MEMORY_SCOPE_AGENT);
            const unsigned target = 16u * (unsigned)(t + 1);
            while (__hip_atomic_load(cnt, __ATOMIC_RELAXED, __HIP_MEMORY_SCOPE_AGENT) < target)
                __builtin_amdgcn_s_sleep(2);
        }
        __syncthreads();
    }
}

extern "C" void kernel_launch(void* const* d_in, const int* in_sizes, int n_in,
                              void* d_out, int out_size, void* d_ws, size_t ws_size,
                              hipStream_t stream) {
    const float* x  = (const float*)d_in[0];
    const float* h0 = (const float*)d_in[1];
    const float* Wi = (const float*)d_in[2];
    const float* b  = (const float*)d_in[3];
    const float* Wr = (const float*)d_in[4];
    float* out = (float*)d_out;

    unsigned* bar = (unsigned*)d_ws;                       // 4 KB counters
    const size_t wit_bytes = (size_t)Uu * Dd * 2;          // 1 MB each
    uint16_t* WiT_hi = (uint16_t*)((char*)d_ws + 8192);
    uint16_t* WiT_lo = (uint16_t*)((char*)d_ws + 8192 + wit_bytes);
    const bool ws_ok = ws_size >= 8192 + 2 * wit_bytes;

    init_bar_kernel<<<1, 1024, 0, stream>>>(bar);

    if (ws_ok) {
        wi_split_kernel<<<dim3(Dd / 32, Uu / 32), 256, 0, stream>>>(Wi, WiT_hi, WiT_lo);
        xi_mfma_kernel<<<dim3((Bb * Tt) / 64, Uu / 256), 512, 0, stream>>>(
            x, WiT_hi, WiT_lo, b, out);
    } else {
        xi_gemm_kernel<<<dim3((Bb * Tt) / 64, Uu / 64), 256, 0, stream>>>(x, Wi, b, out);
    }

    // scan: r8-proven config, unconditional (256 blocks = 1 wg/CU, wide margin)
    void* args[] = { (void*)&Wr, (void*)&h0, (void*)&out, (void*)&bar };
    hipLaunchCooperativeKernel((const void*)scan_kernel1, dim3(256), dim3(512),
                               args, 0, stream);
}